// Round 8
// baseline (670.834 us; speedup 1.0000x reference)
//
#include <hip/hip_runtime.h>
#include <math.h>

#define N_NODES 131072
#define N_EDGES 2097152
#define DIM     64
#define BSUB    4096
#define NREL    3
#define NBASES  2
#define NCB     256     // coarse buckets (dst >> 9)
#define CBSZ    8192    // edges per chist/cscatter block (256 blocks exactly)

typedef unsigned short u16;
typedef __attribute__((ext_vector_type(8))) short bf16x8;   // MFMA A/B frag (4 VGPRs)
typedef __attribute__((ext_vector_type(4))) float f32x4;    // MFMA C/D frag

__device__ __forceinline__ float bf2f(u16 x) {
    return __uint_as_float(((unsigned)x) << 16);
}
__device__ __forceinline__ u16 f2bf(float f) {
    unsigned u = __float_as_uint(f);
    unsigned r = (u + 0x7FFFu + ((u >> 16) & 1u)) >> 16;   // RNE
    return (u16)r;
}
__device__ __forceinline__ float4 bf4_to_f4(ushort4 u) {
    return make_float4(bf2f(u.x), bf2f(u.y), bf2f(u.z), bf2f(u.w));
}
__device__ __forceinline__ ushort4 f4_to_bf4(float4 v) {
    ushort4 o; o.x = f2bf(v.x); o.y = f2bf(v.y); o.z = f2bf(v.z); o.w = f2bf(v.w);
    return o;
}

// ================= R17: MSD bucket sort replaces atomic CSR build ==============
// R2-R5 established: global returning atomics are capped ~24 G/s chip-wide,
// invariant to line padding (R14), per-wave ILP (R15), and atomic scope (R16)
// — they execute memory-side (32 B/atomic WRITE traffic signature). This sort
// uses only LDS atomics per edge + 65K global atomics per pass (negligible).

// ---------------- init: mark centers + zero coarse histogram ----------------
__global__ void initmark_kernel(int* __restrict__ mark, int* __restrict__ chist) {
    int i = blockIdx.x * 256 + threadIdx.x;
    if (i < N_NODES) mark[i] = (i < BSUB) ? 1 : 0;
    if (i < NCB) chist[i] = 0;
}

// ---------------- pass A: coarse histogram (dst >> 9) ----------------
__global__ __launch_bounds__(256) void chist_kernel(const int* __restrict__ dst,
                                                    int* __restrict__ chist) {
    __shared__ int lh[NCB];
    int tid = threadIdx.x;
    lh[tid] = 0;
    __syncthreads();
    int base = blockIdx.x * CBSZ + tid;
#pragma unroll
    for (int j = 0; j < CBSZ / 256; j++)
        atomicAdd(&lh[dst[base + j * 256] >> 9], 1);
    __syncthreads();
    atomicAdd(&chist[tid], lh[tid]);     // non-returning, 256/block
}

// ---------------- coarse scan: chist -> cbase (excl) + ccur copy ----------------
__global__ void cscan_kernel(const int* __restrict__ chist, int* __restrict__ cbase,
                             int* __restrict__ ccur, int* __restrict__ offs) {
    __shared__ int s[NCB];
    int tid = threadIdx.x;
    int v = chist[tid];
    s[tid] = v;
    __syncthreads();
    int val = v;
    for (int off = 1; off < NCB; off <<= 1) {
        int tmp = (tid >= off) ? s[tid - off] : 0;
        __syncthreads();
        val += tmp;
        s[tid] = val;
        __syncthreads();
    }
    cbase[tid] = val - v;
    ccur[tid] = val - v;
    if (tid == 0) offs[N_NODES] = N_EDGES;
}

// ---------------- pass B: coarse scatter (full payload) + frontier mark --------
// Each block: LDS-hist its 8192 edges, claim per-bin runs (256 returning
// global atomics/block = 65K total), scatter {src|et, m1, m2, dst} into tmp.
__global__ __launch_bounds__(256) void cscatter_kernel(
    const int* __restrict__ src, const int* __restrict__ dst,
    const int* __restrict__ et, const float* __restrict__ m1,
    const float* __restrict__ m2, int* __restrict__ ccur,
    int4* __restrict__ tmp, int* __restrict__ mark) {
    __shared__ int lh[NCB];
    __shared__ int lbase[NCB];
    int tid = threadIdx.x;
    lh[tid] = 0;
    __syncthreads();
    int e0 = blockIdx.x * CBSZ;
#pragma unroll
    for (int j = 0; j < CBSZ / 256; j++)
        atomicAdd(&lh[dst[e0 + tid + j * 256] >> 9], 1);
    __syncthreads();
    int c = lh[tid];
    lbase[tid] = c ? atomicAdd(&ccur[tid], c) : 0;
    lh[tid] = 0;                 // reuse as local cursor
    __syncthreads();
#pragma unroll
    for (int j = 0; j < CBSZ / 256; j++) {
        int e = e0 + tid + j * 256;
        int d = dst[e];
        int s = src[e];
        int b = d >> 9;
        int r = atomicAdd(&lh[b], 1);            // LDS returning
        int4 v;
        v.x = s | (et[e] << 20);
        v.y = __float_as_int(m1[e]);
        v.z = __float_as_int(m2[e]);
        v.w = d;
        tmp[lbase[b] + r] = v;
        if (d < BSUB) mark[s] = 1;               // benign race: all write 1
    }
}

// ---------------- pass C: fine scatter within coarse bucket + offs write -------
// One WG per bucket (512 nodes, ~8192 edges, 128 KB csr region -> XCD-L2-local).
// LDS 512-bin hist + scan -> offs[] directly; then scatter csr by LDS ranks.
__global__ __launch_bounds__(256) void fscatter_kernel(
    const int4* __restrict__ tmp, const int* __restrict__ cbase,
    const int* __restrict__ chist, int* __restrict__ offs,
    int4* __restrict__ csr) {
    __shared__ int lh[512];
    __shared__ int lpre[512];
    __shared__ int s2[256];
    int b = blockIdx.x;
    int tid = threadIdx.x;
    int base = cbase[b], cnt = chist[b];
    lh[tid] = 0; lh[tid + 256] = 0;
    __syncthreads();
    for (int i = tid; i < cnt; i += 256)
        atomicAdd(&lh[tmp[base + i].w & 511], 1);
    __syncthreads();
    // exclusive scan of 512 bins (pair + 256-scan + expand)
    int a0 = lh[2 * tid], a1 = lh[2 * tid + 1];
    s2[tid] = a0 + a1;
    __syncthreads();
    int val = s2[tid];
    for (int off = 1; off < 256; off <<= 1) {
        int t = (tid >= off) ? s2[tid - off] : 0;
        __syncthreads();
        val += t;
        s2[tid] = val;
        __syncthreads();
    }
    int ex = val - (a0 + a1);
    lpre[2 * tid] = ex;
    lpre[2 * tid + 1] = ex + a0;
    // offs for this bucket's 512 nodes
    offs[b * 512 + 2 * tid]     = base + ex;
    offs[b * 512 + 2 * tid + 1] = base + ex + a0;
    lh[tid] = 0; lh[tid + 256] = 0;    // reuse as cursors
    __syncthreads();
    for (int i = tid; i < cnt; i += 256) {
        int4 v = tmp[base + i];
        int k = v.w & 511;
        int r = atomicAdd(&lh[k], 1);            // LDS returning
        csr[base + lpre[k] + r] = v;             // .w carries dst (agg ignores)
    }
}

// block-level exclusive scan of 256 ints; block total -> bsum (mark compaction)
__global__ void scan1_kernel(const int* __restrict__ cnt, int* __restrict__ scanned,
                             int* __restrict__ bsum) {
    __shared__ int s[256];
    int tid = threadIdx.x;
    int i = blockIdx.x * 256 + tid;
    int v = cnt[i];
    s[tid] = v;
    __syncthreads();
    int val = v;
    for (int off = 1; off < 256; off <<= 1) {
        int tmp = (tid >= off) ? s[tid - off] : 0;
        __syncthreads();
        val += tmp;
        s[tid] = val;
        __syncthreads();
    }
    scanned[i] = val - v;                 // exclusive
    if (tid == 255) bsum[blockIdx.x] = val;
}

// exclusive scan of 512 block sums, in place
__global__ void scan2_kernel(int* __restrict__ bsum) {
    __shared__ int s[512];
    int tid = threadIdx.x;
    int v = bsum[tid];
    s[tid] = v;
    __syncthreads();
    int val = v;
    for (int off = 1; off < 512; off <<= 1) {
        int tmp = (tid >= off) ? s[tid - off] : 0;
        __syncthreads();
        val += tmp;
        s[tid] = val;
        __syncthreads();
    }
    bsum[tid] = val - v;
}

// compact marked nodes -> list[], write count to nld
__global__ void listfill_kernel(const int* __restrict__ mark, const int* __restrict__ mpref,
                                const int* __restrict__ mbsum, int* __restrict__ list,
                                int* __restrict__ nld) {
    int i = blockIdx.x * 256 + threadIdx.x;
    int pos = mpref[i] + mbsum[blockIdx.x];
    if (mark[i]) list[pos] = i;
    if (i == N_NODES - 1) *nld = pos + mark[i];
}

// ---------------- x -> bf16 convert ----------------
__global__ void cvt_kernel(const float4* __restrict__ x, ushort4* __restrict__ hb, int n4) {
    int i = blockIdx.x * 256 + threadIdx.x;
    if (i < n4) hb[i] = f4_to_bf4(x[i]);
}

// ---------------- weight packing into MFMA B-fragment layout ----------------
// Wc[192][64]: rows 0..63 = V_b0, 64..127 = V_b1, 128..191 = W_self.
// wfrag[conv][nt(4)][kidx(6)][lane(64)][j(8)]; n = nt*16+(lane&15),
// k = kidx*32+(lane>>4)*8+j.
__global__ void wpack_kernel(const float* __restrict__ lV, const float* __restrict__ lW,
                             const float* __restrict__ gV, const float* __restrict__ gW,
                             u16* __restrict__ wfrag) {
    int idx = blockIdx.x * 256 + threadIdx.x;   // 6*4*6*64 = 9216
    if (idx >= 6 * 4 * 6 * 64) return;
    int lane = idx & 63;
    int kidx = (idx >> 6) % 6;
    int nt   = (idx >> 6) / 6 % 4;
    int c    = idx / (64 * 6 * 4);      // conv 0..5
    int layer = c >> 1;
    bool isglobal = c & 1;
    const float* V = isglobal ? gV : lV;
    const float* W = isglobal ? gW : lW;
    int n = nt * 16 + (lane & 15);
    int kbase = kidx * 32 + (lane >> 4) * 8;
    u16 vals[8];
#pragma unroll
    for (int j = 0; j < 8; j++) {
        int r = kbase + j;      // 0..191
        float val;
        if (r < NBASES * DIM) {
            int b = r >> 6, d = r & 63;
            val = V[((layer * NBASES + b) * DIM + d) * DIM + n];
        } else {
            int d = r - NBASES * DIM;
            val = W[(layer * DIM + d) * DIM + n];
        }
        vals[j] = f2bf(val);
    }
    ushort4* o = (ushort4*)(wfrag + (size_t)idx * 8);
    o[0] = make_ushort4(vals[0], vals[1], vals[2], vals[3]);
    o[1] = make_ushort4(vals[4], vals[5], vals[6], vals[7]);
}

// ---------------- edge aggregation (wave per dst node, basis-space, bf16 h) ------
// R18: LDS meta-stage (decode per edge once; zero-coef padding kills bounds
// logic in the inner loop).
// R19: wave-uniform early break in the s-loop. Degrees ~ Poisson(16) so the
// fixed 32-slot inner loop was ~50% zero-coef padding (full gather + 8 FMA
// wasted per padded slot). The s-group covers edges j+4s..j+4s+3; cnt is
// wave-uniform, so `j+4s >= cnt` is a scalar s_cbranch that stops the unroll
// at the boundary WITHOUT waiting on outstanding loads (keeps the 8-deep
// gather pipeline for high-degree nodes).
__global__ __launch_bounds__(256) void agg_kernel(
    const ushort4* __restrict__ hb, const int* __restrict__ offs,
    const int4* __restrict__ csr, const float* __restrict__ Cc,
    int which, ushort4* __restrict__ t, int nNodes,
    const int* __restrict__ list, const int* __restrict__ nld) {
    __shared__ int4 lmeta[4][64];
    int lane = threadIdx.x & 63;
    int wid  = threadIdx.x >> 6;
    int idx = (blockIdx.x << 2) + wid;
    int n;
    if (list) {
        if (idx >= *nld) return;
        n = list[idx];
    } else {
        if (idx >= nNodes) return;
        n = idx;
    }
    int q  = lane >> 4;     // quarter 0..3
    int ql = lane & 15;     // lane within quarter
    float Ca0 = Cc[0], Cb0 = Cc[1], Ca1 = Cc[2], Cb1 = Cc[3], Ca2 = Cc[4], Cb2 = Cc[5];
    int beg = offs[n], end = offs[n + 1];
    float4 a0 = make_float4(0.f, 0.f, 0.f, 0.f);
    float4 a1 = make_float4(0.f, 0.f, 0.f, 0.f);
    for (int base = beg; base < end; base += 64) {
        int cnt = min(64, end - base);
        int pp = 0; float c0 = 0.f, c1 = 0.f;
        if (lane < cnt) {
            int4 meta = csr[base + lane];
            int et = ((unsigned)meta.x) >> 20;
            float m = __int_as_float(which ? meta.z : meta.y);
            float ca = et == 0 ? Ca0 : (et == 1 ? Ca1 : Ca2);
            float cb = et == 0 ? Cb0 : (et == 1 ? Cb1 : Cb2);
            pp = (meta.x & 0xFFFFF) << 4;        // pre-scaled hb row base
            c0 = m * ca;
            c1 = m * cb;
        }
        lmeta[wid][lane] = make_int4(pp, __float_as_int(c0), __float_as_int(c1), 0);
        // wave-local LDS: compiler inserts lgkmcnt ordering; no cross-wave use
        for (int j = 0; j < cnt; j += 32) {
#pragma unroll
            for (int s = 0; s < 8; s++) {
                if (j + (s << 2) >= cnt) break;           // wave-uniform: all-pad group
                int4 md = lmeta[wid][j + (s << 2) + q];   // broadcast per quarter
                ushort4 rv = hb[md.x + ql];
                float4 v = bf4_to_f4(rv);
                float e0 = __int_as_float(md.y);
                float e1 = __int_as_float(md.z);
                a0.x = fmaf(e0, v.x, a0.x); a0.y = fmaf(e0, v.y, a0.y);
                a0.z = fmaf(e0, v.z, a0.z); a0.w = fmaf(e0, v.w, a0.w);
                a1.x = fmaf(e1, v.x, a1.x); a1.y = fmaf(e1, v.y, a1.y);
                a1.z = fmaf(e1, v.z, a1.z); a1.w = fmaf(e1, v.w, a1.w);
            }
        }
    }
#pragma unroll
    for (int off = 16; off < 64; off <<= 1) {
        a0.x += __shfl_xor(a0.x, off, 64); a0.y += __shfl_xor(a0.y, off, 64);
        a0.z += __shfl_xor(a0.z, off, 64); a0.w += __shfl_xor(a0.w, off, 64);
        a1.x += __shfl_xor(a1.x, off, 64); a1.y += __shfl_xor(a1.y, off, 64);
        a1.z += __shfl_xor(a1.z, off, 64); a1.w += __shfl_xor(a1.w, off, 64);
    }
    ushort4 outv = f4_to_bf4(q == 0 ? a0 : a1);
    if (q < 2)
        t[(size_t)n * 32 + (q << 4) + ql] = outv;
}

// ---------------- MFMA GEMM: [rows,128(t)|64(h self)] @ wfrag[192,64] -----------
// 4 waves/block; wave owns 16 row-slots x 64 cols; K = 6 x mfma_f32_16x16x32_bf16
// (kidx 0..3 A from t, kidx 4..5 A from h). list: indirect rows (layer-2 local).
__global__ __launch_bounds__(256) void gemm_kernel(
    const u16* __restrict__ t, const u16* __restrict__ h,
    const u16* __restrict__ wfrag, const float* __restrict__ bias,
    u16* __restrict__ hout, float* __restrict__ subg, int subg_off, int act,
    const int* __restrict__ list, const int* __restrict__ nld) {
    int tid = threadIdx.x;
    int wave = tid >> 6, lane = tid & 63;
    int l16 = lane & 15, quad = lane >> 4;
    int nL = list ? *nld : 0;
    if (list && blockIdx.x * 64 >= nL) return;
    int slot0 = blockIdx.x * 64 + wave * 16;
    int myslot = slot0 + l16;
    int rowA = list ? list[min(myslot, nL - 1)] : myslot;
    const u16* trow = t + (size_t)rowA * 128;
    const u16* hrow = h + (size_t)rowA * 64;
    f32x4 acc0 = {0.f, 0.f, 0.f, 0.f};
    f32x4 acc1 = {0.f, 0.f, 0.f, 0.f};
    f32x4 acc2 = {0.f, 0.f, 0.f, 0.f};
    f32x4 acc3 = {0.f, 0.f, 0.f, 0.f};
#pragma unroll
    for (int kidx = 0; kidx < 6; kidx++) {
        bf16x8 a = (kidx < 4)
            ? *(const bf16x8*)(trow + kidx * 32 + quad * 8)
            : *(const bf16x8*)(hrow + (kidx - 4) * 32 + quad * 8);
        bf16x8 b0 = *(const bf16x8*)(wfrag + ((size_t)(0 * 6 + kidx) * 64 + lane) * 8);
        bf16x8 b1 = *(const bf16x8*)(wfrag + ((size_t)(1 * 6 + kidx) * 64 + lane) * 8);
        bf16x8 b2 = *(const bf16x8*)(wfrag + ((size_t)(2 * 6 + kidx) * 64 + lane) * 8);
        bf16x8 b3 = *(const bf16x8*)(wfrag + ((size_t)(3 * 6 + kidx) * 64 + lane) * 8);
        acc0 = __builtin_amdgcn_mfma_f32_16x16x32_bf16(a, b0, acc0, 0, 0, 0);
        acc1 = __builtin_amdgcn_mfma_f32_16x16x32_bf16(a, b1, acc1, 0, 0, 0);
        acc2 = __builtin_amdgcn_mfma_f32_16x16x32_bf16(a, b2, acc2, 0, 0, 0);
        acc3 = __builtin_amdgcn_mfma_f32_16x16x32_bf16(a, b3, acc3, 0, 0, 0);
    }
    float accs[4][4] = {
        {acc0[0], acc0[1], acc0[2], acc0[3]},
        {acc1[0], acc1[1], acc1[2], acc1[3]},
        {acc2[0], acc2[1], acc2[2], acc2[3]},
        {acc3[0], acc3[1], acc3[2], acc3[3]},
    };
#pragma unroll
    for (int nt = 0; nt < 4; nt++) {
        int col = nt * 16 + l16;
        float bcol = bias[col];
#pragma unroll
        for (int r = 0; r < 4; r++) {
            int cslot = slot0 + quad * 4 + r;
            if (list && cslot >= nL) continue;
            int row = list ? __shfl(rowA, quad * 4 + r, 64) : cslot;
            float xv = accs[nt][r] + bcol;
            float v = act ? (xv > 0.f ? xv : 0.01f * xv)
                          : (xv > 0.f ? xv : expm1f(xv));
            hout[(size_t)row * 64 + col] = f2bf(v);
            if (subg && row < BSUB)
                subg[(size_t)row * 192 + subg_off + col] = v;
        }
    }
}

// ---------------- MLP head: [4096,192] -> relu 128 -> sigmoid 1 ----------------
__global__ __launch_bounds__(256) void head_kernel(
    const float* __restrict__ subg, const float* __restrict__ w1,
    const float* __restrict__ b1, const float* __restrict__ w2,
    const float* __restrict__ b2, float* __restrict__ out) {
    __shared__ float srow[4][192];
    int lane = threadIdx.x & 63, wid = threadIdx.x >> 6;
    int row = blockIdx.x * 4 + wid;
    const float* sr = subg + (size_t)row * 192;
    srow[wid][lane] = sr[lane];
    srow[wid][64 + lane] = sr[64 + lane];
    srow[wid][128 + lane] = sr[128 + lane];
    __syncthreads();
    float acc1 = b1[lane], acc2 = b1[64 + lane];
    const float* w1a = w1 + lane * 192;
    const float* w1b = w1 + (64 + lane) * 192;
    for (int k = 0; k < 192; k++) {
        float s = srow[wid][k];
        acc1 = fmaf(s, w1a[k], acc1);
        acc2 = fmaf(s, w1b[k], acc2);
    }
    acc1 = fmaxf(acc1, 0.f);
    acc2 = fmaxf(acc2, 0.f);
    float part = acc1 * w2[lane] + acc2 * w2[64 + lane];
    for (int off = 32; off; off >>= 1) part += __shfl_down(part, off, 64);
    if (lane == 0) out[row] = 1.f / (1.f + expf(-(part + b2[0])));
}

extern "C" void kernel_launch(void* const* d_in, const int* in_sizes, int n_in,
                              void* d_out, int out_size, void* d_ws, size_t ws_size,
                              hipStream_t stream) {
    const float* x     = (const float*)d_in[0];
    const int*   src   = (const int*)d_in[1];
    const int*   dst   = (const int*)d_in[2];
    const int*   etype = (const int*)d_in[3];
    const float* mask  = (const float*)d_in[4];
    const float* mask2 = (const float*)d_in[5];
    const float* lV = (const float*)d_in[6];
    const float* lC = (const float*)d_in[7];
    const float* lW = (const float*)d_in[8];
    const float* lB = (const float*)d_in[9];
    const float* gV = (const float*)d_in[10];
    const float* gC = (const float*)d_in[11];
    const float* gW = (const float*)d_in[12];
    const float* gB = (const float*)d_in[13];
    const float* w1 = (const float*)d_in[14];
    const float* b1 = (const float*)d_in[15];
    const float* w2 = (const float*)d_in[16];
    const float* b2 = (const float*)d_in[17];
    float* out = (float*)d_out;

    // workspace carve-up
    char* ws = (char*)d_ws;
    size_t off = 0;
    auto alloc = [&](size_t bytes) {
        void* p = ws + off;
        off += (bytes + 255) & ~(size_t)255;
        return p;
    };
    ushort4* h    = (ushort4*)alloc((size_t)N_NODES * 64 * 2);     // bf16 [N,64]
    ushort4* t    = (ushort4*)alloc((size_t)N_NODES * 128 * 2);    // bf16 [N,128]
    int4*  csr    = (int4*)alloc((size_t)N_EDGES * 16);
    int*   offs   = (int*)alloc((size_t)(N_NODES + 1) * 4);
    int*   chist  = (int*)alloc(NCB * 4);
    int*   cbase  = (int*)alloc(NCB * 4);
    int*   ccur   = (int*)alloc(NCB * 4);
    int*   bsum   = (int*)alloc(512 * 4);
    int*   mark   = (int*)alloc((size_t)N_NODES * 4);
    int*   mpref  = (int*)alloc((size_t)N_NODES * 4);
    int*   mbsum  = (int*)alloc(512 * 4);
    int*   list   = (int*)alloc((size_t)N_NODES * 4);
    int*   nld    = (int*)alloc(256);
    u16*   wfrag  = (u16*)alloc((size_t)6 * 4 * 6 * 64 * 8 * 2);
    float* subg   = (float*)alloc((size_t)BSUB * 192 * 4);
    // tmp (coarse-sorted payload, 32 MB) aliases t: t is dead until agg.
    int4*  tmp    = (int4*)t;

    // ---- graph preprocessing (R17 sort pipeline) ----
    initmark_kernel<<<N_NODES / 256, 256, 0, stream>>>(mark, chist);
    chist_kernel<<<NCB, 256, 0, stream>>>(dst, chist);
    cscan_kernel<<<1, NCB, 0, stream>>>(chist, cbase, ccur, offs);
    cscatter_kernel<<<NCB, 256, 0, stream>>>(src, dst, etype, mask, mask2,
                                             ccur, tmp, mark);
    fscatter_kernel<<<NCB, 256, 0, stream>>>(tmp, cbase, chist, offs, csr);
    // frontier compaction for layer-2 local conv
    scan1_kernel<<<N_NODES / 256, 256, 0, stream>>>(mark, mpref, mbsum);
    scan2_kernel<<<1, 512, 0, stream>>>(mbsum);
    listfill_kernel<<<N_NODES / 256, 256, 0, stream>>>(mark, mpref, mbsum, list, nld);
    wpack_kernel<<<(6 * 4 * 6 * 64 + 255) / 256, 256, 0, stream>>>(lV, lW, gV, gW, wfrag);
    cvt_kernel<<<(N_NODES * 64 / 4) / 256, 256, 0, stream>>>((const float4*)x, h,
                                                             N_NODES * 64 / 4);

    const int convfrag = 4 * 6 * 64 * 8;   // u16 elements per conv
    for (int layer = 0; layer < 3; layer++) {
        // local conv (mask, elu); layer 2: frontier-pruned
        const int* ll  = (layer == 2) ? list : nullptr;
        agg_kernel<<<N_NODES / 4, 256, 0, stream>>>(h, offs, csr,
            lC + layer * NREL * NBASES, 0, t, N_NODES, ll, nld);
        gemm_kernel<<<N_NODES / 64, 256, 0, stream>>>(
            (const u16*)t, (const u16*)h,
            wfrag + (size_t)(layer * 2 + 0) * convfrag, lB + layer * 64,
            (u16*)h, nullptr, 0, 0, ll, nld);
        // global conv (mask2, leaky_relu); layer 2: only BSUB rows
        int nG = (layer == 2) ? BSUB : N_NODES;
        agg_kernel<<<(nG + 3) / 4, 256, 0, stream>>>(h, offs, csr,
            gC + layer * NREL * NBASES, 1, t, nG, nullptr, nld);
        gemm_kernel<<<nG / 64, 256, 0, stream>>>(
            (const u16*)t, (const u16*)h,
            wfrag + (size_t)(layer * 2 + 1) * convfrag, gB + layer * 64,
            (u16*)h, subg, layer * 64, 1, nullptr, nld);
    }
    head_kernel<<<BSUB / 4, 256, 0, stream>>>(subg, w1, b1, w2, b2, out);
}

// Round 9
// 622.176 us; speedup vs baseline: 1.0782x; 1.0782x over previous
//
#include <hip/hip_runtime.h>
#include <math.h>

#define N_NODES 131072
#define N_EDGES 2097152
#define DIM     64
#define BSUB    4096
#define NREL    3
#define NBASES  2
#define NCB     256     // coarse buckets (dst >> 9)
#define CBSZ    8192    // edges per chist/cscatter block (256 blocks exactly)

typedef unsigned short u16;
typedef __attribute__((ext_vector_type(8))) short bf16x8;   // MFMA A/B frag (4 VGPRs)
typedef __attribute__((ext_vector_type(4))) float f32x4;    // MFMA C/D frag

__device__ __forceinline__ float bf2f(u16 x) {
    return __uint_as_float(((unsigned)x) << 16);
}
__device__ __forceinline__ u16 f2bf(float f) {
    unsigned u = __float_as_uint(f);
    unsigned r = (u + 0x7FFFu + ((u >> 16) & 1u)) >> 16;   // RNE
    return (u16)r;
}
__device__ __forceinline__ float4 bf4_to_f4(ushort4 u) {
    return make_float4(bf2f(u.x), bf2f(u.y), bf2f(u.z), bf2f(u.w));
}
__device__ __forceinline__ ushort4 f4_to_bf4(float4 v) {
    ushort4 o; o.x = f2bf(v.x); o.y = f2bf(v.y); o.z = f2bf(v.z); o.w = f2bf(v.w);
    return o;
}

// ================= R17: MSD bucket sort replaces atomic CSR build ==============
// R2-R5 established: global returning atomics are capped ~24 G/s chip-wide,
// invariant to line padding (R14), per-wave ILP (R15), and atomic scope (R16)
// — they execute memory-side (32 B/atomic WRITE traffic signature). This sort
// uses only LDS atomics per edge + 65K global atomics per pass (negligible).

// ---------------- init: mark centers + zero coarse histogram ----------------
__global__ void initmark_kernel(int* __restrict__ mark, int* __restrict__ chist) {
    int i = blockIdx.x * 256 + threadIdx.x;
    if (i < N_NODES) mark[i] = (i < BSUB) ? 1 : 0;
    if (i < NCB) chist[i] = 0;
}

// ---------------- pass A: coarse histogram (dst >> 9) ----------------
__global__ __launch_bounds__(256) void chist_kernel(const int* __restrict__ dst,
                                                    int* __restrict__ chist) {
    __shared__ int lh[NCB];
    int tid = threadIdx.x;
    lh[tid] = 0;
    __syncthreads();
    int base = blockIdx.x * CBSZ + tid;
#pragma unroll
    for (int j = 0; j < CBSZ / 256; j++)
        atomicAdd(&lh[dst[base + j * 256] >> 9], 1);
    __syncthreads();
    atomicAdd(&chist[tid], lh[tid]);     // non-returning, 256/block
}

// ---------------- coarse scan: chist -> cbase (excl) + ccur copy ----------------
__global__ void cscan_kernel(const int* __restrict__ chist, int* __restrict__ cbase,
                             int* __restrict__ ccur, int* __restrict__ offs) {
    __shared__ int s[NCB];
    int tid = threadIdx.x;
    int v = chist[tid];
    s[tid] = v;
    __syncthreads();
    int val = v;
    for (int off = 1; off < NCB; off <<= 1) {
        int tmp = (tid >= off) ? s[tid - off] : 0;
        __syncthreads();
        val += tmp;
        s[tid] = val;
        __syncthreads();
    }
    cbase[tid] = val - v;
    ccur[tid] = val - v;
    if (tid == 0) offs[N_NODES] = N_EDGES;
}

// ---------------- pass B: coarse scatter (full payload) + frontier mark --------
// Each block: LDS-hist its 8192 edges, claim per-bin runs (256 returning
// global atomics/block = 65K total), scatter {src|et, m1, m2, dst} into tmp.
__global__ __launch_bounds__(256) void cscatter_kernel(
    const int* __restrict__ src, const int* __restrict__ dst,
    const int* __restrict__ et, const float* __restrict__ m1,
    const float* __restrict__ m2, int* __restrict__ ccur,
    int4* __restrict__ tmp, int* __restrict__ mark) {
    __shared__ int lh[NCB];
    __shared__ int lbase[NCB];
    int tid = threadIdx.x;
    lh[tid] = 0;
    __syncthreads();
    int e0 = blockIdx.x * CBSZ;
#pragma unroll
    for (int j = 0; j < CBSZ / 256; j++)
        atomicAdd(&lh[dst[e0 + tid + j * 256] >> 9], 1);
    __syncthreads();
    int c = lh[tid];
    lbase[tid] = c ? atomicAdd(&ccur[tid], c) : 0;
    lh[tid] = 0;                 // reuse as local cursor
    __syncthreads();
#pragma unroll
    for (int j = 0; j < CBSZ / 256; j++) {
        int e = e0 + tid + j * 256;
        int d = dst[e];
        int s = src[e];
        int b = d >> 9;
        int r = atomicAdd(&lh[b], 1);            // LDS returning
        int4 v;
        v.x = s | (et[e] << 20);
        v.y = __float_as_int(m1[e]);
        v.z = __float_as_int(m2[e]);
        v.w = d;
        tmp[lbase[b] + r] = v;
        if (d < BSUB) mark[s] = 1;               // benign race: all write 1
    }
}

// ---------------- pass C: fine scatter within coarse bucket + offs write -------
// One WG per bucket (512 nodes, ~8192 edges, 128 KB csr region -> XCD-L2-local).
// LDS 512-bin hist + scan -> offs[] directly; then scatter csr by LDS ranks.
__global__ __launch_bounds__(256) void fscatter_kernel(
    const int4* __restrict__ tmp, const int* __restrict__ cbase,
    const int* __restrict__ chist, int* __restrict__ offs,
    int4* __restrict__ csr) {
    __shared__ int lh[512];
    __shared__ int lpre[512];
    __shared__ int s2[256];
    int b = blockIdx.x;
    int tid = threadIdx.x;
    int base = cbase[b], cnt = chist[b];
    lh[tid] = 0; lh[tid + 256] = 0;
    __syncthreads();
    for (int i = tid; i < cnt; i += 256)
        atomicAdd(&lh[tmp[base + i].w & 511], 1);
    __syncthreads();
    // exclusive scan of 512 bins (pair + 256-scan + expand)
    int a0 = lh[2 * tid], a1 = lh[2 * tid + 1];
    s2[tid] = a0 + a1;
    __syncthreads();
    int val = s2[tid];
    for (int off = 1; off < 256; off <<= 1) {
        int t = (tid >= off) ? s2[tid - off] : 0;
        __syncthreads();
        val += t;
        s2[tid] = val;
        __syncthreads();
    }
    int ex = val - (a0 + a1);
    lpre[2 * tid] = ex;
    lpre[2 * tid + 1] = ex + a0;
    // offs for this bucket's 512 nodes
    offs[b * 512 + 2 * tid]     = base + ex;
    offs[b * 512 + 2 * tid + 1] = base + ex + a0;
    lh[tid] = 0; lh[tid + 256] = 0;    // reuse as cursors
    __syncthreads();
    for (int i = tid; i < cnt; i += 256) {
        int4 v = tmp[base + i];
        int k = v.w & 511;
        int r = atomicAdd(&lh[k], 1);            // LDS returning
        csr[base + lpre[k] + r] = v;             // .w carries dst (agg ignores)
    }
}

// block-level exclusive scan of 256 ints; block total -> bsum (mark compaction)
__global__ void scan1_kernel(const int* __restrict__ cnt, int* __restrict__ scanned,
                             int* __restrict__ bsum) {
    __shared__ int s[256];
    int tid = threadIdx.x;
    int i = blockIdx.x * 256 + tid;
    int v = cnt[i];
    s[tid] = v;
    __syncthreads();
    int val = v;
    for (int off = 1; off < 256; off <<= 1) {
        int tmp = (tid >= off) ? s[tid - off] : 0;
        __syncthreads();
        val += tmp;
        s[tid] = val;
        __syncthreads();
    }
    scanned[i] = val - v;                 // exclusive
    if (tid == 255) bsum[blockIdx.x] = val;
}

// exclusive scan of 512 block sums, in place
__global__ void scan2_kernel(int* __restrict__ bsum) {
    __shared__ int s[512];
    int tid = threadIdx.x;
    int v = bsum[tid];
    s[tid] = v;
    __syncthreads();
    int val = v;
    for (int off = 1; off < 512; off <<= 1) {
        int tmp = (tid >= off) ? s[tid - off] : 0;
        __syncthreads();
        val += tmp;
        s[tid] = val;
        __syncthreads();
    }
    bsum[tid] = val - v;
}

// compact marked nodes -> list[], write count to nld
__global__ void listfill_kernel(const int* __restrict__ mark, const int* __restrict__ mpref,
                                const int* __restrict__ mbsum, int* __restrict__ list,
                                int* __restrict__ nld) {
    int i = blockIdx.x * 256 + threadIdx.x;
    int pos = mpref[i] + mbsum[blockIdx.x];
    if (mark[i]) list[pos] = i;
    if (i == N_NODES - 1) *nld = pos + mark[i];
}

// ---------------- x -> bf16 convert ----------------
__global__ void cvt_kernel(const float4* __restrict__ x, ushort4* __restrict__ hb, int n4) {
    int i = blockIdx.x * 256 + threadIdx.x;
    if (i < n4) hb[i] = f4_to_bf4(x[i]);
}

// ---------------- weight packing into MFMA B-fragment layout ----------------
// Wc[192][64]: rows 0..63 = V_b0, 64..127 = V_b1, 128..191 = W_self.
// wfrag[conv][nt(4)][kidx(6)][lane(64)][j(8)]; n = nt*16+(lane&15),
// k = kidx*32+(lane>>4)*8+j.
__global__ void wpack_kernel(const float* __restrict__ lV, const float* __restrict__ lW,
                             const float* __restrict__ gV, const float* __restrict__ gW,
                             u16* __restrict__ wfrag) {
    int idx = blockIdx.x * 256 + threadIdx.x;   // 6*4*6*64 = 9216
    if (idx >= 6 * 4 * 6 * 64) return;
    int lane = idx & 63;
    int kidx = (idx >> 6) % 6;
    int nt   = (idx >> 6) / 6 % 4;
    int c    = idx / (64 * 6 * 4);      // conv 0..5
    int layer = c >> 1;
    bool isglobal = c & 1;
    const float* V = isglobal ? gV : lV;
    const float* W = isglobal ? gW : lW;
    int n = nt * 16 + (lane & 15);
    int kbase = kidx * 32 + (lane >> 4) * 8;
    u16 vals[8];
#pragma unroll
    for (int j = 0; j < 8; j++) {
        int r = kbase + j;      // 0..191
        float val;
        if (r < NBASES * DIM) {
            int b = r >> 6, d = r & 63;
            val = V[((layer * NBASES + b) * DIM + d) * DIM + n];
        } else {
            int d = r - NBASES * DIM;
            val = W[(layer * DIM + d) * DIM + n];
        }
        vals[j] = f2bf(val);
    }
    ushort4* o = (ushort4*)(wfrag + (size_t)idx * 8);
    o[0] = make_ushort4(vals[0], vals[1], vals[2], vals[3]);
    o[1] = make_ushort4(vals[4], vals[5], vals[6], vals[7]);
}

// ---------------- edge aggregation (wave per dst node, basis-space, bf16 h) ------
// R18: LDS meta-stage (decode per edge once; zero-coef padding kills bounds
// logic in the inner loop).
// R20: 16-slot groups (4 s-steps, straight-line). R19's per-group break killed
// load batching (VGPR 40->16, ~2 gathers in flight) and was a wash. A 4-step
// unrolled body with loop trip ceil(cnt/16) keeps 4 lmeta-reads + 4 gathers
// in flight AND caps padding at 15 edges (expected slots ~23 vs R18's 32 for
// Poisson(16) degrees).
__global__ __launch_bounds__(256) void agg_kernel(
    const ushort4* __restrict__ hb, const int* __restrict__ offs,
    const int4* __restrict__ csr, const float* __restrict__ Cc,
    int which, ushort4* __restrict__ t, int nNodes,
    const int* __restrict__ list, const int* __restrict__ nld) {
    __shared__ int4 lmeta[4][64];
    int lane = threadIdx.x & 63;
    int wid  = threadIdx.x >> 6;
    int idx = (blockIdx.x << 2) + wid;
    int n;
    if (list) {
        if (idx >= *nld) return;
        n = list[idx];
    } else {
        if (idx >= nNodes) return;
        n = idx;
    }
    int q  = lane >> 4;     // quarter 0..3
    int ql = lane & 15;     // lane within quarter
    float Ca0 = Cc[0], Cb0 = Cc[1], Ca1 = Cc[2], Cb1 = Cc[3], Ca2 = Cc[4], Cb2 = Cc[5];
    int beg = offs[n], end = offs[n + 1];
    float4 a0 = make_float4(0.f, 0.f, 0.f, 0.f);
    float4 a1 = make_float4(0.f, 0.f, 0.f, 0.f);
    for (int base = beg; base < end; base += 64) {
        int cnt = min(64, end - base);
        int pp = 0; float c0 = 0.f, c1 = 0.f;
        if (lane < cnt) {
            int4 meta = csr[base + lane];
            int et = ((unsigned)meta.x) >> 20;
            float m = __int_as_float(which ? meta.z : meta.y);
            float ca = et == 0 ? Ca0 : (et == 1 ? Ca1 : Ca2);
            float cb = et == 0 ? Cb0 : (et == 1 ? Cb1 : Cb2);
            pp = (meta.x & 0xFFFFF) << 4;        // pre-scaled hb row base
            c0 = m * ca;
            c1 = m * cb;
        }
        lmeta[wid][lane] = make_int4(pp, __float_as_int(c0), __float_as_int(c1), 0);
        // wave-local LDS: compiler inserts lgkmcnt ordering; no cross-wave use
        for (int j = 0; j < cnt; j += 16) {
#pragma unroll
            for (int s = 0; s < 4; s++) {
                int4 md = lmeta[wid][j + (s << 2) + q];   // broadcast per quarter
                ushort4 rv = hb[md.x + ql];
                float4 v = bf4_to_f4(rv);
                float e0 = __int_as_float(md.y);
                float e1 = __int_as_float(md.z);
                a0.x = fmaf(e0, v.x, a0.x); a0.y = fmaf(e0, v.y, a0.y);
                a0.z = fmaf(e0, v.z, a0.z); a0.w = fmaf(e0, v.w, a0.w);
                a1.x = fmaf(e1, v.x, a1.x); a1.y = fmaf(e1, v.y, a1.y);
                a1.z = fmaf(e1, v.z, a1.z); a1.w = fmaf(e1, v.w, a1.w);
            }
        }
    }
#pragma unroll
    for (int off = 16; off < 64; off <<= 1) {
        a0.x += __shfl_xor(a0.x, off, 64); a0.y += __shfl_xor(a0.y, off, 64);
        a0.z += __shfl_xor(a0.z, off, 64); a0.w += __shfl_xor(a0.w, off, 64);
        a1.x += __shfl_xor(a1.x, off, 64); a1.y += __shfl_xor(a1.y, off, 64);
        a1.z += __shfl_xor(a1.z, off, 64); a1.w += __shfl_xor(a1.w, off, 64);
    }
    ushort4 outv = f4_to_bf4(q == 0 ? a0 : a1);
    if (q < 2)
        t[(size_t)n * 32 + (q << 4) + ql] = outv;
}

// ---------------- MFMA GEMM: [rows,128(t)|64(h self)] @ wfrag[192,64] -----------
// 4 waves/block; wave owns 16 row-slots x 64 cols; K = 6 x mfma_f32_16x16x32_bf16
// (kidx 0..3 A from t, kidx 4..5 A from h). list: indirect rows (layer-2 local).
__global__ __launch_bounds__(256) void gemm_kernel(
    const u16* __restrict__ t, const u16* __restrict__ h,
    const u16* __restrict__ wfrag, const float* __restrict__ bias,
    u16* __restrict__ hout, float* __restrict__ subg, int subg_off, int act,
    const int* __restrict__ list, const int* __restrict__ nld) {
    int tid = threadIdx.x;
    int wave = tid >> 6, lane = tid & 63;
    int l16 = lane & 15, quad = lane >> 4;
    int nL = list ? *nld : 0;
    if (list && blockIdx.x * 64 >= nL) return;
    int slot0 = blockIdx.x * 64 + wave * 16;
    int myslot = slot0 + l16;
    int rowA = list ? list[min(myslot, nL - 1)] : myslot;
    const u16* trow = t + (size_t)rowA * 128;
    const u16* hrow = h + (size_t)rowA * 64;
    f32x4 acc0 = {0.f, 0.f, 0.f, 0.f};
    f32x4 acc1 = {0.f, 0.f, 0.f, 0.f};
    f32x4 acc2 = {0.f, 0.f, 0.f, 0.f};
    f32x4 acc3 = {0.f, 0.f, 0.f, 0.f};
#pragma unroll
    for (int kidx = 0; kidx < 6; kidx++) {
        bf16x8 a = (kidx < 4)
            ? *(const bf16x8*)(trow + kidx * 32 + quad * 8)
            : *(const bf16x8*)(hrow + (kidx - 4) * 32 + quad * 8);
        bf16x8 b0 = *(const bf16x8*)(wfrag + ((size_t)(0 * 6 + kidx) * 64 + lane) * 8);
        bf16x8 b1 = *(const bf16x8*)(wfrag + ((size_t)(1 * 6 + kidx) * 64 + lane) * 8);
        bf16x8 b2 = *(const bf16x8*)(wfrag + ((size_t)(2 * 6 + kidx) * 64 + lane) * 8);
        bf16x8 b3 = *(const bf16x8*)(wfrag + ((size_t)(3 * 6 + kidx) * 64 + lane) * 8);
        acc0 = __builtin_amdgcn_mfma_f32_16x16x32_bf16(a, b0, acc0, 0, 0, 0);
        acc1 = __builtin_amdgcn_mfma_f32_16x16x32_bf16(a, b1, acc1, 0, 0, 0);
        acc2 = __builtin_amdgcn_mfma_f32_16x16x32_bf16(a, b2, acc2, 0, 0, 0);
        acc3 = __builtin_amdgcn_mfma_f32_16x16x32_bf16(a, b3, acc3, 0, 0, 0);
    }
    float accs[4][4] = {
        {acc0[0], acc0[1], acc0[2], acc0[3]},
        {acc1[0], acc1[1], acc1[2], acc1[3]},
        {acc2[0], acc2[1], acc2[2], acc2[3]},
        {acc3[0], acc3[1], acc3[2], acc3[3]},
    };
#pragma unroll
    for (int nt = 0; nt < 4; nt++) {
        int col = nt * 16 + l16;
        float bcol = bias[col];
#pragma unroll
        for (int r = 0; r < 4; r++) {
            int cslot = slot0 + quad * 4 + r;
            if (list && cslot >= nL) continue;
            int row = list ? __shfl(rowA, quad * 4 + r, 64) : cslot;
            float xv = accs[nt][r] + bcol;
            float v = act ? (xv > 0.f ? xv : 0.01f * xv)
                          : (xv > 0.f ? xv : expm1f(xv));
            hout[(size_t)row * 64 + col] = f2bf(v);
            if (subg && row < BSUB)
                subg[(size_t)row * 192 + subg_off + col] = v;
        }
    }
}

// ---------------- MLP head: [4096,192] -> relu 128 -> sigmoid 1 ----------------
__global__ __launch_bounds__(256) void head_kernel(
    const float* __restrict__ subg, const float* __restrict__ w1,
    const float* __restrict__ b1, const float* __restrict__ w2,
    const float* __restrict__ b2, float* __restrict__ out) {
    __shared__ float srow[4][192];
    int lane = threadIdx.x & 63, wid = threadIdx.x >> 6;
    int row = blockIdx.x * 4 + wid;
    const float* sr = subg + (size_t)row * 192;
    srow[wid][lane] = sr[lane];
    srow[wid][64 + lane] = sr[64 + lane];
    srow[wid][128 + lane] = sr[128 + lane];
    __syncthreads();
    float acc1 = b1[lane], acc2 = b1[64 + lane];
    const float* w1a = w1 + lane * 192;
    const float* w1b = w1 + (64 + lane) * 192;
    for (int k = 0; k < 192; k++) {
        float s = srow[wid][k];
        acc1 = fmaf(s, w1a[k], acc1);
        acc2 = fmaf(s, w1b[k], acc2);
    }
    acc1 = fmaxf(acc1, 0.f);
    acc2 = fmaxf(acc2, 0.f);
    float part = acc1 * w2[lane] + acc2 * w2[64 + lane];
    for (int off = 32; off; off >>= 1) part += __shfl_down(part, off, 64);
    if (lane == 0) out[row] = 1.f / (1.f + expf(-(part + b2[0])));
}

extern "C" void kernel_launch(void* const* d_in, const int* in_sizes, int n_in,
                              void* d_out, int out_size, void* d_ws, size_t ws_size,
                              hipStream_t stream) {
    const float* x     = (const float*)d_in[0];
    const int*   src   = (const int*)d_in[1];
    const int*   dst   = (const int*)d_in[2];
    const int*   etype = (const int*)d_in[3];
    const float* mask  = (const float*)d_in[4];
    const float* mask2 = (const float*)d_in[5];
    const float* lV = (const float*)d_in[6];
    const float* lC = (const float*)d_in[7];
    const float* lW = (const float*)d_in[8];
    const float* lB = (const float*)d_in[9];
    const float* gV = (const float*)d_in[10];
    const float* gC = (const float*)d_in[11];
    const float* gW = (const float*)d_in[12];
    const float* gB = (const float*)d_in[13];
    const float* w1 = (const float*)d_in[14];
    const float* b1 = (const float*)d_in[15];
    const float* w2 = (const float*)d_in[16];
    const float* b2 = (const float*)d_in[17];
    float* out = (float*)d_out;

    // workspace carve-up
    char* ws = (char*)d_ws;
    size_t off = 0;
    auto alloc = [&](size_t bytes) {
        void* p = ws + off;
        off += (bytes + 255) & ~(size_t)255;
        return p;
    };
    ushort4* h    = (ushort4*)alloc((size_t)N_NODES * 64 * 2);     // bf16 [N,64]
    ushort4* t    = (ushort4*)alloc((size_t)N_NODES * 128 * 2);    // bf16 [N,128]
    int4*  csr    = (int4*)alloc((size_t)N_EDGES * 16);
    int*   offs   = (int*)alloc((size_t)(N_NODES + 1) * 4);
    int*   chist  = (int*)alloc(NCB * 4);
    int*   cbase  = (int*)alloc(NCB * 4);
    int*   ccur   = (int*)alloc(NCB * 4);
    int*   bsum   = (int*)alloc(512 * 4);
    int*   mark   = (int*)alloc((size_t)N_NODES * 4);
    int*   mpref  = (int*)alloc((size_t)N_NODES * 4);
    int*   mbsum  = (int*)alloc(512 * 4);
    int*   list   = (int*)alloc((size_t)N_NODES * 4);
    int*   nld    = (int*)alloc(256);
    u16*   wfrag  = (u16*)alloc((size_t)6 * 4 * 6 * 64 * 8 * 2);
    float* subg   = (float*)alloc((size_t)BSUB * 192 * 4);
    // tmp (coarse-sorted payload, 32 MB) aliases t: t is dead until agg.
    int4*  tmp    = (int4*)t;

    // ---- graph preprocessing (R17 sort pipeline) ----
    initmark_kernel<<<N_NODES / 256, 256, 0, stream>>>(mark, chist);
    chist_kernel<<<NCB, 256, 0, stream>>>(dst, chist);
    cscan_kernel<<<1, NCB, 0, stream>>>(chist, cbase, ccur, offs);
    cscatter_kernel<<<NCB, 256, 0, stream>>>(src, dst, etype, mask, mask2,
                                             ccur, tmp, mark);
    fscatter_kernel<<<NCB, 256, 0, stream>>>(tmp, cbase, chist, offs, csr);
    // frontier compaction for layer-2 local conv
    scan1_kernel<<<N_NODES / 256, 256, 0, stream>>>(mark, mpref, mbsum);
    scan2_kernel<<<1, 512, 0, stream>>>(mbsum);
    listfill_kernel<<<N_NODES / 256, 256, 0, stream>>>(mark, mpref, mbsum, list, nld);
    wpack_kernel<<<(6 * 4 * 6 * 64 + 255) / 256, 256, 0, stream>>>(lV, lW, gV, gW, wfrag);
    cvt_kernel<<<(N_NODES * 64 / 4) / 256, 256, 0, stream>>>((const float4*)x, h,
                                                             N_NODES * 64 / 4);

    const int convfrag = 4 * 6 * 64 * 8;   // u16 elements per conv
    for (int layer = 0; layer < 3; layer++) {
        // local conv (mask, elu); layer 2: frontier-pruned
        const int* ll  = (layer == 2) ? list : nullptr;
        agg_kernel<<<N_NODES / 4, 256, 0, stream>>>(h, offs, csr,
            lC + layer * NREL * NBASES, 0, t, N_NODES, ll, nld);
        gemm_kernel<<<N_NODES / 64, 256, 0, stream>>>(
            (const u16*)t, (const u16*)h,
            wfrag + (size_t)(layer * 2 + 0) * convfrag, lB + layer * 64,
            (u16*)h, nullptr, 0, 0, ll, nld);
        // global conv (mask2, leaky_relu); layer 2: only BSUB rows
        int nG = (layer == 2) ? BSUB : N_NODES;
        agg_kernel<<<(nG + 3) / 4, 256, 0, stream>>>(h, offs, csr,
            gC + layer * NREL * NBASES, 1, t, nG, nullptr, nld);
        gemm_kernel<<<nG / 64, 256, 0, stream>>>(
            (const u16*)t, (const u16*)h,
            wfrag + (size_t)(layer * 2 + 1) * convfrag, gB + layer * 64,
            (u16*)h, subg, layer * 64, 1, nullptr, nld);
    }
    head_kernel<<<BSUB / 4, 256, 0, stream>>>(subg, w1, b1, w2, b2, out);
}

// Round 10
// 603.347 us; speedup vs baseline: 1.1119x; 1.0312x over previous
//
#include <hip/hip_runtime.h>
#include <math.h>

#define N_NODES 131072
#define N_EDGES 2097152
#define DIM     64
#define BSUB    4096
#define NREL    3
#define NBASES  2
#define NCB     512     // coarse buckets (dst >> 8), 256 nodes each
#define CBSZ    8192    // edges per chist/cscatter block (256 blocks exactly)

typedef unsigned short u16;
typedef __attribute__((ext_vector_type(8))) short bf16x8;   // MFMA A/B frag (4 VGPRs)
typedef __attribute__((ext_vector_type(4))) float f32x4;    // MFMA C/D frag

__device__ __forceinline__ float bf2f(u16 x) {
    return __uint_as_float(((unsigned)x) << 16);
}
__device__ __forceinline__ u16 f2bf(float f) {
    unsigned u = __float_as_uint(f);
    unsigned r = (u + 0x7FFFu + ((u >> 16) & 1u)) >> 16;   // RNE
    return (u16)r;
}
__device__ __forceinline__ float4 bf4_to_f4(ushort4 u) {
    return make_float4(bf2f(u.x), bf2f(u.y), bf2f(u.z), bf2f(u.w));
}
__device__ __forceinline__ ushort4 f4_to_bf4(float4 v) {
    ushort4 o; o.x = f2bf(v.x); o.y = f2bf(v.y); o.z = f2bf(v.z); o.w = f2bf(v.w);
    return o;
}

// ================= R17/R21: MSD bucket sort replaces atomic CSR build ==========
// R2-R5: global returning atomics capped ~24 G/s chip-wide (invariant to
// padding/ILP/scope — memory-side execution). Sort uses LDS atomics per edge +
// ~131K global claim atomics (few µs).
// R21: R9 counters showed cscatter at 8.5% occupancy, VALU 1.5%, HBM 14% —
// pure unhidden latency (1 block/CU, 32 serial {load+LDS-atomic+store} iters).
// Re-shaped: 512 coarse buckets (dst>>8); cscatter 512 threads + 4-edge ILP
// (4 serial iters); fscatter 512 blocks (2/CU) + 4-edge unroll.

// ---------------- init: mark centers + zero coarse histogram ----------------
__global__ void initmark_kernel(int* __restrict__ mark, int* __restrict__ chist) {
    int i = blockIdx.x * 256 + threadIdx.x;
    if (i < N_NODES) mark[i] = (i < BSUB) ? 1 : 0;
    if (i < NCB) chist[i] = 0;
}

// ---------------- pass A: coarse histogram (dst >> 8) ----------------
__global__ __launch_bounds__(256) void chist_kernel(const int* __restrict__ dst,
                                                    int* __restrict__ chist) {
    __shared__ int lh[NCB];
    int tid = threadIdx.x;
    lh[tid] = 0; lh[tid + 256] = 0;
    __syncthreads();
    int base = blockIdx.x * CBSZ;
#pragma unroll
    for (int j = 0; j < CBSZ / 1024; j++) {          // 8 iters, 4 edges/thread
        int4 d4 = *(const int4*)(dst + base + j * 1024 + tid * 4);
        atomicAdd(&lh[d4.x >> 8], 1);
        atomicAdd(&lh[d4.y >> 8], 1);
        atomicAdd(&lh[d4.z >> 8], 1);
        atomicAdd(&lh[d4.w >> 8], 1);
    }
    __syncthreads();
    atomicAdd(&chist[tid], lh[tid]);                 // non-returning
    atomicAdd(&chist[tid + 256], lh[tid + 256]);
}

// ---------------- coarse scan: chist -> cbase (excl) + ccur copy ----------------
__global__ void cscan_kernel(const int* __restrict__ chist, int* __restrict__ cbase,
                             int* __restrict__ ccur, int* __restrict__ offs) {
    __shared__ int s[NCB];
    int tid = threadIdx.x;        // 512 threads
    int v = chist[tid];
    s[tid] = v;
    __syncthreads();
    int val = v;
    for (int off = 1; off < NCB; off <<= 1) {
        int tmp = (tid >= off) ? s[tid - off] : 0;
        __syncthreads();
        val += tmp;
        s[tid] = val;
        __syncthreads();
    }
    cbase[tid] = val - v;
    ccur[tid] = val - v;
    if (tid == 0) offs[N_NODES] = N_EDGES;
}

// ---------------- pass B: coarse scatter (full payload) + frontier mark --------
// 256 blocks x 512 threads (8 waves/CU); per-thread 4-edge ILP, 4 iterations.
// Claim: 512 returning global atomics/block (~131K total, ~5 µs, overlapped).
__global__ __launch_bounds__(512) void cscatter_kernel(
    const int* __restrict__ src, const int* __restrict__ dst,
    const int* __restrict__ et, const float* __restrict__ m1,
    const float* __restrict__ m2, int* __restrict__ ccur,
    int4* __restrict__ tmp, int* __restrict__ mark) {
    __shared__ int lh[NCB];
    __shared__ int lbase[NCB];
    int tid = threadIdx.x;        // 0..511
    lh[tid] = 0;
    __syncthreads();
    int e0b = blockIdx.x * CBSZ;
#pragma unroll
    for (int j = 0; j < CBSZ / 2048; j++) {          // 4 iters
        int4 d4 = *(const int4*)(dst + e0b + j * 2048 + tid * 4);
        atomicAdd(&lh[d4.x >> 8], 1);
        atomicAdd(&lh[d4.y >> 8], 1);
        atomicAdd(&lh[d4.z >> 8], 1);
        atomicAdd(&lh[d4.w >> 8], 1);
    }
    __syncthreads();
    int c = lh[tid];
    lbase[tid] = c ? atomicAdd(&ccur[tid], c) : 0;   // returning, 512/block
    lh[tid] = 0;                 // reuse as local cursor (own-slot only)
    __syncthreads();
#pragma unroll
    for (int j = 0; j < CBSZ / 2048; j++) {
        int e0 = e0b + j * 2048 + tid * 4;
        int4  d4 = *(const int4*)(dst + e0);
        int4  s4 = *(const int4*)(src + e0);
        int4  t4 = *(const int4*)(et + e0);
        float4 a4 = *(const float4*)(m1 + e0);
        float4 b4 = *(const float4*)(m2 + e0);
#pragma unroll
        for (int k = 0; k < 4; k++) {
            int d = (&d4.x)[k];
            int s = (&s4.x)[k];
            int b = d >> 8;
            int r = atomicAdd(&lh[b], 1);            // LDS returning
            int4 v;
            v.x = s | ((&t4.x)[k] << 20);
            v.y = __float_as_int((&a4.x)[k]);
            v.z = __float_as_int((&b4.x)[k]);
            v.w = d;
            tmp[lbase[b] + r] = v;
            if (d < BSUB) mark[s] = 1;               // benign race: all write 1
        }
    }
}

// ---------------- pass C: fine scatter within coarse bucket + offs write -------
// 512 blocks (2/CU), one per bucket (256 nodes, ~4096 edges, 64 KB csr region).
// LDS 256-bin hist + scan -> offs[] directly; scatter csr by LDS ranks.
// 4-edge unrolled main loop + strided tail.
__global__ __launch_bounds__(256) void fscatter_kernel(
    const int4* __restrict__ tmp, const int* __restrict__ cbase,
    const int* __restrict__ chist, int* __restrict__ offs,
    int4* __restrict__ csr) {
    __shared__ int lh[256];
    __shared__ int lpre[256];
    __shared__ int s[256];
    int b = blockIdx.x;
    int tid = threadIdx.x;
    int base = cbase[b], cnt = chist[b];
    lh[tid] = 0;
    __syncthreads();
    int i = 0;
    for (; i + 1024 <= cnt; i += 1024) {
        int4 v0 = tmp[base + i + tid * 4 + 0];
        int4 v1 = tmp[base + i + tid * 4 + 1];
        int4 v2 = tmp[base + i + tid * 4 + 2];
        int4 v3 = tmp[base + i + tid * 4 + 3];
        atomicAdd(&lh[v0.w & 255], 1);
        atomicAdd(&lh[v1.w & 255], 1);
        atomicAdd(&lh[v2.w & 255], 1);
        atomicAdd(&lh[v3.w & 255], 1);
    }
    for (int k = i + tid; k < cnt; k += 256)
        atomicAdd(&lh[tmp[base + k].w & 255], 1);
    __syncthreads();
    // exclusive scan of 256 bins
    int v = lh[tid];
    s[tid] = v;
    __syncthreads();
    int val = v;
    for (int off = 1; off < 256; off <<= 1) {
        int tq = (tid >= off) ? s[tid - off] : 0;
        __syncthreads();
        val += tq;
        s[tid] = val;
        __syncthreads();
    }
    int ex = val - v;
    lpre[tid] = ex;
    offs[b * 256 + tid] = base + ex;     // offs for this bucket's 256 nodes
    lh[tid] = 0;                          // reuse as cursors
    __syncthreads();
    i = 0;
    for (; i + 1024 <= cnt; i += 1024) {
        int4 v0 = tmp[base + i + tid * 4 + 0];
        int4 v1 = tmp[base + i + tid * 4 + 1];
        int4 v2 = tmp[base + i + tid * 4 + 2];
        int4 v3 = tmp[base + i + tid * 4 + 3];
        int k0 = v0.w & 255; int r0 = atomicAdd(&lh[k0], 1); csr[base + lpre[k0] + r0] = v0;
        int k1 = v1.w & 255; int r1 = atomicAdd(&lh[k1], 1); csr[base + lpre[k1] + r1] = v1;
        int k2 = v2.w & 255; int r2 = atomicAdd(&lh[k2], 1); csr[base + lpre[k2] + r2] = v2;
        int k3 = v3.w & 255; int r3 = atomicAdd(&lh[k3], 1); csr[base + lpre[k3] + r3] = v3;
    }
    for (int kk = i + tid; kk < cnt; kk += 256) {
        int4 vv = tmp[base + kk];
        int k = vv.w & 255;
        int r = atomicAdd(&lh[k], 1);
        csr[base + lpre[k] + r] = vv;                // .w carries dst (agg ignores)
    }
}

// block-level exclusive scan of 256 ints; block total -> bsum (mark compaction)
__global__ void scan1_kernel(const int* __restrict__ cnt, int* __restrict__ scanned,
                             int* __restrict__ bsum) {
    __shared__ int s[256];
    int tid = threadIdx.x;
    int i = blockIdx.x * 256 + tid;
    int v = cnt[i];
    s[tid] = v;
    __syncthreads();
    int val = v;
    for (int off = 1; off < 256; off <<= 1) {
        int tmp = (tid >= off) ? s[tid - off] : 0;
        __syncthreads();
        val += tmp;
        s[tid] = val;
        __syncthreads();
    }
    scanned[i] = val - v;                 // exclusive
    if (tid == 255) bsum[blockIdx.x] = val;
}

// exclusive scan of 512 block sums, in place
__global__ void scan2_kernel(int* __restrict__ bsum) {
    __shared__ int s[512];
    int tid = threadIdx.x;
    int v = bsum[tid];
    s[tid] = v;
    __syncthreads();
    int val = v;
    for (int off = 1; off < 512; off <<= 1) {
        int tmp = (tid >= off) ? s[tid - off] : 0;
        __syncthreads();
        val += tmp;
        s[tid] = val;
        __syncthreads();
    }
    bsum[tid] = val - v;
}

// compact marked nodes -> list[], write count to nld
__global__ void listfill_kernel(const int* __restrict__ mark, const int* __restrict__ mpref,
                                const int* __restrict__ mbsum, int* __restrict__ list,
                                int* __restrict__ nld) {
    int i = blockIdx.x * 256 + threadIdx.x;
    int pos = mpref[i] + mbsum[blockIdx.x];
    if (mark[i]) list[pos] = i;
    if (i == N_NODES - 1) *nld = pos + mark[i];
}

// ---------------- x -> bf16 convert ----------------
__global__ void cvt_kernel(const float4* __restrict__ x, ushort4* __restrict__ hb, int n4) {
    int i = blockIdx.x * 256 + threadIdx.x;
    if (i < n4) hb[i] = f4_to_bf4(x[i]);
}

// ---------------- weight packing into MFMA B-fragment layout ----------------
// Wc[192][64]: rows 0..63 = V_b0, 64..127 = V_b1, 128..191 = W_self.
// wfrag[conv][nt(4)][kidx(6)][lane(64)][j(8)]; n = nt*16+(lane&15),
// k = kidx*32+(lane>>4)*8+j.
__global__ void wpack_kernel(const float* __restrict__ lV, const float* __restrict__ lW,
                             const float* __restrict__ gV, const float* __restrict__ gW,
                             u16* __restrict__ wfrag) {
    int idx = blockIdx.x * 256 + threadIdx.x;   // 6*4*6*64 = 9216
    if (idx >= 6 * 4 * 6 * 64) return;
    int lane = idx & 63;
    int kidx = (idx >> 6) % 6;
    int nt   = (idx >> 6) / 6 % 4;
    int c    = idx / (64 * 6 * 4);      // conv 0..5
    int layer = c >> 1;
    bool isglobal = c & 1;
    const float* V = isglobal ? gV : lV;
    const float* W = isglobal ? gW : lW;
    int n = nt * 16 + (lane & 15);
    int kbase = kidx * 32 + (lane >> 4) * 8;
    u16 vals[8];
#pragma unroll
    for (int j = 0; j < 8; j++) {
        int r = kbase + j;      // 0..191
        float val;
        if (r < NBASES * DIM) {
            int b = r >> 6, d = r & 63;
            val = V[((layer * NBASES + b) * DIM + d) * DIM + n];
        } else {
            int d = r - NBASES * DIM;
            val = W[(layer * DIM + d) * DIM + n];
        }
        vals[j] = f2bf(val);
    }
    ushort4* o = (ushort4*)(wfrag + (size_t)idx * 8);
    o[0] = make_ushort4(vals[0], vals[1], vals[2], vals[3]);
    o[1] = make_ushort4(vals[4], vals[5], vals[6], vals[7]);
}

// ---------------- edge aggregation (wave per dst node, basis-space, bf16 h) ------
// R18: LDS meta-stage (decode per edge once; zero-coef padding kills bounds
// logic in the inner loop).
// R20: 16-slot groups (4 s-steps, straight-line): keeps 4 lmeta-reads +
// 4 gathers in flight AND caps padding at 15 edges (~23 slots avg vs 32).
__global__ __launch_bounds__(256) void agg_kernel(
    const ushort4* __restrict__ hb, const int* __restrict__ offs,
    const int4* __restrict__ csr, const float* __restrict__ Cc,
    int which, ushort4* __restrict__ t, int nNodes,
    const int* __restrict__ list, const int* __restrict__ nld) {
    __shared__ int4 lmeta[4][64];
    int lane = threadIdx.x & 63;
    int wid  = threadIdx.x >> 6;
    int idx = (blockIdx.x << 2) + wid;
    int n;
    if (list) {
        if (idx >= *nld) return;
        n = list[idx];
    } else {
        if (idx >= nNodes) return;
        n = idx;
    }
    int q  = lane >> 4;     // quarter 0..3
    int ql = lane & 15;     // lane within quarter
    float Ca0 = Cc[0], Cb0 = Cc[1], Ca1 = Cc[2], Cb1 = Cc[3], Ca2 = Cc[4], Cb2 = Cc[5];
    int beg = offs[n], end = offs[n + 1];
    float4 a0 = make_float4(0.f, 0.f, 0.f, 0.f);
    float4 a1 = make_float4(0.f, 0.f, 0.f, 0.f);
    for (int base = beg; base < end; base += 64) {
        int cnt = min(64, end - base);
        int pp = 0; float c0 = 0.f, c1 = 0.f;
        if (lane < cnt) {
            int4 meta = csr[base + lane];
            int et = ((unsigned)meta.x) >> 20;
            float m = __int_as_float(which ? meta.z : meta.y);
            float ca = et == 0 ? Ca0 : (et == 1 ? Ca1 : Ca2);
            float cb = et == 0 ? Cb0 : (et == 1 ? Cb1 : Cb2);
            pp = (meta.x & 0xFFFFF) << 4;        // pre-scaled hb row base
            c0 = m * ca;
            c1 = m * cb;
        }
        lmeta[wid][lane] = make_int4(pp, __float_as_int(c0), __float_as_int(c1), 0);
        // wave-local LDS: compiler inserts lgkmcnt ordering; no cross-wave use
        for (int j = 0; j < cnt; j += 16) {
#pragma unroll
            for (int s = 0; s < 4; s++) {
                int4 md = lmeta[wid][j + (s << 2) + q];   // broadcast per quarter
                ushort4 rv = hb[md.x + ql];
                float4 v = bf4_to_f4(rv);
                float e0 = __int_as_float(md.y);
                float e1 = __int_as_float(md.z);
                a0.x = fmaf(e0, v.x, a0.x); a0.y = fmaf(e0, v.y, a0.y);
                a0.z = fmaf(e0, v.z, a0.z); a0.w = fmaf(e0, v.w, a0.w);
                a1.x = fmaf(e1, v.x, a1.x); a1.y = fmaf(e1, v.y, a1.y);
                a1.z = fmaf(e1, v.z, a1.z); a1.w = fmaf(e1, v.w, a1.w);
            }
        }
    }
#pragma unroll
    for (int off = 16; off < 64; off <<= 1) {
        a0.x += __shfl_xor(a0.x, off, 64); a0.y += __shfl_xor(a0.y, off, 64);
        a0.z += __shfl_xor(a0.z, off, 64); a0.w += __shfl_xor(a0.w, off, 64);
        a1.x += __shfl_xor(a1.x, off, 64); a1.y += __shfl_xor(a1.y, off, 64);
        a1.z += __shfl_xor(a1.z, off, 64); a1.w += __shfl_xor(a1.w, off, 64);
    }
    ushort4 outv = f4_to_bf4(q == 0 ? a0 : a1);
    if (q < 2)
        t[(size_t)n * 32 + (q << 4) + ql] = outv;
}

// ---------------- MFMA GEMM: [rows,128(t)|64(h self)] @ wfrag[192,64] -----------
// 4 waves/block; wave owns 16 row-slots x 64 cols; K = 6 x mfma_f32_16x16x32_bf16
// (kidx 0..3 A from t, kidx 4..5 A from h). list: indirect rows (layer-2 local).
__global__ __launch_bounds__(256) void gemm_kernel(
    const u16* __restrict__ t, const u16* __restrict__ h,
    const u16* __restrict__ wfrag, const float* __restrict__ bias,
    u16* __restrict__ hout, float* __restrict__ subg, int subg_off, int act,
    const int* __restrict__ list, const int* __restrict__ nld) {
    int tid = threadIdx.x;
    int wave = tid >> 6, lane = tid & 63;
    int l16 = lane & 15, quad = lane >> 4;
    int nL = list ? *nld : 0;
    if (list && blockIdx.x * 64 >= nL) return;
    int slot0 = blockIdx.x * 64 + wave * 16;
    int myslot = slot0 + l16;
    int rowA = list ? list[min(myslot, nL - 1)] : myslot;
    const u16* trow = t + (size_t)rowA * 128;
    const u16* hrow = h + (size_t)rowA * 64;
    f32x4 acc0 = {0.f, 0.f, 0.f, 0.f};
    f32x4 acc1 = {0.f, 0.f, 0.f, 0.f};
    f32x4 acc2 = {0.f, 0.f, 0.f, 0.f};
    f32x4 acc3 = {0.f, 0.f, 0.f, 0.f};
#pragma unroll
    for (int kidx = 0; kidx < 6; kidx++) {
        bf16x8 a = (kidx < 4)
            ? *(const bf16x8*)(trow + kidx * 32 + quad * 8)
            : *(const bf16x8*)(hrow + (kidx - 4) * 32 + quad * 8);
        bf16x8 b0 = *(const bf16x8*)(wfrag + ((size_t)(0 * 6 + kidx) * 64 + lane) * 8);
        bf16x8 b1 = *(const bf16x8*)(wfrag + ((size_t)(1 * 6 + kidx) * 64 + lane) * 8);
        bf16x8 b2 = *(const bf16x8*)(wfrag + ((size_t)(2 * 6 + kidx) * 64 + lane) * 8);
        bf16x8 b3 = *(const bf16x8*)(wfrag + ((size_t)(3 * 6 + kidx) * 64 + lane) * 8);
        acc0 = __builtin_amdgcn_mfma_f32_16x16x32_bf16(a, b0, acc0, 0, 0, 0);
        acc1 = __builtin_amdgcn_mfma_f32_16x16x32_bf16(a, b1, acc1, 0, 0, 0);
        acc2 = __builtin_amdgcn_mfma_f32_16x16x32_bf16(a, b2, acc2, 0, 0, 0);
        acc3 = __builtin_amdgcn_mfma_f32_16x16x32_bf16(a, b3, acc3, 0, 0, 0);
    }
    float accs[4][4] = {
        {acc0[0], acc0[1], acc0[2], acc0[3]},
        {acc1[0], acc1[1], acc1[2], acc1[3]},
        {acc2[0], acc2[1], acc2[2], acc2[3]},
        {acc3[0], acc3[1], acc3[2], acc3[3]},
    };
#pragma unroll
    for (int nt = 0; nt < 4; nt++) {
        int col = nt * 16 + l16;
        float bcol = bias[col];
#pragma unroll
        for (int r = 0; r < 4; r++) {
            int cslot = slot0 + quad * 4 + r;
            if (list && cslot >= nL) continue;
            int row = list ? __shfl(rowA, quad * 4 + r, 64) : cslot;
            float xv = accs[nt][r] + bcol;
            float v = act ? (xv > 0.f ? xv : 0.01f * xv)
                          : (xv > 0.f ? xv : expm1f(xv));
            hout[(size_t)row * 64 + col] = f2bf(v);
            if (subg && row < BSUB)
                subg[(size_t)row * 192 + subg_off + col] = v;
        }
    }
}

// ---------------- MLP head: [4096,192] -> relu 128 -> sigmoid 1 ----------------
__global__ __launch_bounds__(256) void head_kernel(
    const float* __restrict__ subg, const float* __restrict__ w1,
    const float* __restrict__ b1, const float* __restrict__ w2,
    const float* __restrict__ b2, float* __restrict__ out) {
    __shared__ float srow[4][192];
    int lane = threadIdx.x & 63, wid = threadIdx.x >> 6;
    int row = blockIdx.x * 4 + wid;
    const float* sr = subg + (size_t)row * 192;
    srow[wid][lane] = sr[lane];
    srow[wid][64 + lane] = sr[64 + lane];
    srow[wid][128 + lane] = sr[128 + lane];
    __syncthreads();
    float acc1 = b1[lane], acc2 = b1[64 + lane];
    const float* w1a = w1 + lane * 192;
    const float* w1b = w1 + (64 + lane) * 192;
    for (int k = 0; k < 192; k++) {
        float s = srow[wid][k];
        acc1 = fmaf(s, w1a[k], acc1);
        acc2 = fmaf(s, w1b[k], acc2);
    }
    acc1 = fmaxf(acc1, 0.f);
    acc2 = fmaxf(acc2, 0.f);
    float part = acc1 * w2[lane] + acc2 * w2[64 + lane];
    for (int off = 32; off; off >>= 1) part += __shfl_down(part, off, 64);
    if (lane == 0) out[row] = 1.f / (1.f + expf(-(part + b2[0])));
}

extern "C" void kernel_launch(void* const* d_in, const int* in_sizes, int n_in,
                              void* d_out, int out_size, void* d_ws, size_t ws_size,
                              hipStream_t stream) {
    const float* x     = (const float*)d_in[0];
    const int*   src   = (const int*)d_in[1];
    const int*   dst   = (const int*)d_in[2];
    const int*   etype = (const int*)d_in[3];
    const float* mask  = (const float*)d_in[4];
    const float* mask2 = (const float*)d_in[5];
    const float* lV = (const float*)d_in[6];
    const float* lC = (const float*)d_in[7];
    const float* lW = (const float*)d_in[8];
    const float* lB = (const float*)d_in[9];
    const float* gV = (const float*)d_in[10];
    const float* gC = (const float*)d_in[11];
    const float* gW = (const float*)d_in[12];
    const float* gB = (const float*)d_in[13];
    const float* w1 = (const float*)d_in[14];
    const float* b1 = (const float*)d_in[15];
    const float* w2 = (const float*)d_in[16];
    const float* b2 = (const float*)d_in[17];
    float* out = (float*)d_out;

    // workspace carve-up
    char* ws = (char*)d_ws;
    size_t off = 0;
    auto alloc = [&](size_t bytes) {
        void* p = ws + off;
        off += (bytes + 255) & ~(size_t)255;
        return p;
    };
    ushort4* h    = (ushort4*)alloc((size_t)N_NODES * 64 * 2);     // bf16 [N,64]
    ushort4* t    = (ushort4*)alloc((size_t)N_NODES * 128 * 2);    // bf16 [N,128]
    int4*  csr    = (int4*)alloc((size_t)N_EDGES * 16);
    int*   offs   = (int*)alloc((size_t)(N_NODES + 1) * 4);
    int*   chist  = (int*)alloc(NCB * 4);
    int*   cbase  = (int*)alloc(NCB * 4);
    int*   ccur   = (int*)alloc(NCB * 4);
    int*   bsum   = (int*)alloc(512 * 4);
    int*   mark   = (int*)alloc((size_t)N_NODES * 4);
    int*   mpref  = (int*)alloc((size_t)N_NODES * 4);
    int*   mbsum  = (int*)alloc(512 * 4);
    int*   list   = (int*)alloc((size_t)N_NODES * 4);
    int*   nld    = (int*)alloc(256);
    u16*   wfrag  = (u16*)alloc((size_t)6 * 4 * 6 * 64 * 8 * 2);
    float* subg   = (float*)alloc((size_t)BSUB * 192 * 4);
    // tmp (coarse-sorted payload, 32 MB) aliases t: t is dead until agg.
    int4*  tmp    = (int4*)t;

    // ---- graph preprocessing (R17/R21 sort pipeline) ----
    initmark_kernel<<<N_NODES / 256, 256, 0, stream>>>(mark, chist);
    chist_kernel<<<N_EDGES / CBSZ, 256, 0, stream>>>(dst, chist);
    cscan_kernel<<<1, NCB, 0, stream>>>(chist, cbase, ccur, offs);
    cscatter_kernel<<<N_EDGES / CBSZ, 512, 0, stream>>>(src, dst, etype, mask, mask2,
                                                        ccur, tmp, mark);
    fscatter_kernel<<<NCB, 256, 0, stream>>>(tmp, cbase, chist, offs, csr);
    // frontier compaction for layer-2 local conv
    scan1_kernel<<<N_NODES / 256, 256, 0, stream>>>(mark, mpref, mbsum);
    scan2_kernel<<<1, 512, 0, stream>>>(mbsum);
    listfill_kernel<<<N_NODES / 256, 256, 0, stream>>>(mark, mpref, mbsum, list, nld);
    wpack_kernel<<<(6 * 4 * 6 * 64 + 255) / 256, 256, 0, stream>>>(lV, lW, gV, gW, wfrag);
    cvt_kernel<<<(N_NODES * 64 / 4) / 256, 256, 0, stream>>>((const float4*)x, h,
                                                             N_NODES * 64 / 4);

    const int convfrag = 4 * 6 * 64 * 8;   // u16 elements per conv
    for (int layer = 0; layer < 3; layer++) {
        // local conv (mask, elu); layer 2: frontier-pruned
        const int* ll  = (layer == 2) ? list : nullptr;
        agg_kernel<<<N_NODES / 4, 256, 0, stream>>>(h, offs, csr,
            lC + layer * NREL * NBASES, 0, t, N_NODES, ll, nld);
        gemm_kernel<<<N_NODES / 64, 256, 0, stream>>>(
            (const u16*)t, (const u16*)h,
            wfrag + (size_t)(layer * 2 + 0) * convfrag, lB + layer * 64,
            (u16*)h, nullptr, 0, 0, ll, nld);
        // global conv (mask2, leaky_relu); layer 2: only BSUB rows
        int nG = (layer == 2) ? BSUB : N_NODES;
        agg_kernel<<<(nG + 3) / 4, 256, 0, stream>>>(h, offs, csr,
            gC + layer * NREL * NBASES, 1, t, nG, nullptr, nld);
        gemm_kernel<<<nG / 64, 256, 0, stream>>>(
            (const u16*)t, (const u16*)h,
            wfrag + (size_t)(layer * 2 + 1) * convfrag, gB + layer * 64,
            (u16*)h, subg, layer * 64, 1, nullptr, nld);
    }
    head_kernel<<<BSUB / 4, 256, 0, stream>>>(subg, w1, b1, w2, b2, out);
}

// Round 11
// 556.986 us; speedup vs baseline: 1.2044x; 1.0832x over previous
//
#include <hip/hip_runtime.h>
#include <math.h>

#define N_NODES 131072
#define N_EDGES 2097152
#define DIM     64
#define BSUB    4096
#define NREL    3
#define NBASES  2
#define NCB     512     // coarse buckets (dst >> 8), 256 nodes each
#define CBSZ    8192    // edges per chist/cscatter block (256 blocks exactly)

typedef unsigned short u16;
typedef __attribute__((ext_vector_type(8))) short bf16x8;   // MFMA A/B frag (4 VGPRs)
typedef __attribute__((ext_vector_type(4))) float f32x4;    // MFMA C/D frag

__device__ __forceinline__ float bf2f(u16 x) {
    return __uint_as_float(((unsigned)x) << 16);
}
__device__ __forceinline__ u16 f2bf(float f) {
    unsigned u = __float_as_uint(f);
    unsigned r = (u + 0x7FFFu + ((u >> 16) & 1u)) >> 16;   // RNE
    return (u16)r;
}
__device__ __forceinline__ float4 bf4_to_f4(ushort4 u) {
    return make_float4(bf2f(u.x), bf2f(u.y), bf2f(u.z), bf2f(u.w));
}
__device__ __forceinline__ ushort4 f4_to_bf4(float4 v) {
    ushort4 o; o.x = f2bf(v.x); o.y = f2bf(v.y); o.z = f2bf(v.z); o.w = f2bf(v.w);
    return o;
}

// ================= R17/R21: MSD bucket sort replaces atomic CSR build ==========
// R2-R5: global returning atomics capped ~24 G/s chip-wide (invariant to
// padding/ILP/scope — memory-side execution). Sort uses LDS atomics per edge +
// ~131K global claim atomics (few µs).
// R21: 512 coarse buckets (dst>>8); cscatter 512 threads + 4-edge ILP;
// fscatter 512 blocks (2/CU) + 4-edge unroll.
// ================= R22: agg+gemm FUSION (aggmm) =================================
// R10 counters: agg 55.8µs x4 (VALU 65%, occ 70%) + 6 gemms (~100µs below
// top-5). agg wrote t (32 MB, = its exact WRITE_SIZE) and gemm re-read it:
// ~64 MB round-trip per conv, ~275 MB total. Fused: block of 4 waves
// aggregates 16 nodes (4 sequential/wave -> same resident-wave count),
// t-rows go to a padded LDS tile (2-way bank alias only), then each wave
// runs the 6-MFMA k-loop for its 16-col slice and writes h directly.
// h ping-pong (h0/h1) breaks the in-place gather/overwrite hazard; layer-2
// pruned conv safe (conv5 gathers only list∪BSUB rows, all written by conv4).

// ---------------- init: mark centers + zero coarse histogram ----------------
__global__ void initmark_kernel(int* __restrict__ mark, int* __restrict__ chist) {
    int i = blockIdx.x * 256 + threadIdx.x;
    if (i < N_NODES) mark[i] = (i < BSUB) ? 1 : 0;
    if (i < NCB) chist[i] = 0;
}

// ---------------- pass A: coarse histogram (dst >> 8) ----------------
__global__ __launch_bounds__(256) void chist_kernel(const int* __restrict__ dst,
                                                    int* __restrict__ chist) {
    __shared__ int lh[NCB];
    int tid = threadIdx.x;
    lh[tid] = 0; lh[tid + 256] = 0;
    __syncthreads();
    int base = blockIdx.x * CBSZ;
#pragma unroll
    for (int j = 0; j < CBSZ / 1024; j++) {          // 8 iters, 4 edges/thread
        int4 d4 = *(const int4*)(dst + base + j * 1024 + tid * 4);
        atomicAdd(&lh[d4.x >> 8], 1);
        atomicAdd(&lh[d4.y >> 8], 1);
        atomicAdd(&lh[d4.z >> 8], 1);
        atomicAdd(&lh[d4.w >> 8], 1);
    }
    __syncthreads();
    atomicAdd(&chist[tid], lh[tid]);                 // non-returning
    atomicAdd(&chist[tid + 256], lh[tid + 256]);
}

// ---------------- coarse scan: chist -> cbase (excl) + ccur copy ----------------
__global__ void cscan_kernel(const int* __restrict__ chist, int* __restrict__ cbase,
                             int* __restrict__ ccur, int* __restrict__ offs) {
    __shared__ int s[NCB];
    int tid = threadIdx.x;        // 512 threads
    int v = chist[tid];
    s[tid] = v;
    __syncthreads();
    int val = v;
    for (int off = 1; off < NCB; off <<= 1) {
        int tmp = (tid >= off) ? s[tid - off] : 0;
        __syncthreads();
        val += tmp;
        s[tid] = val;
        __syncthreads();
    }
    cbase[tid] = val - v;
    ccur[tid] = val - v;
    if (tid == 0) offs[N_NODES] = N_EDGES;
}

// ---------------- pass B: coarse scatter (full payload) + frontier mark --------
// 256 blocks x 512 threads (8 waves/CU); per-thread 4-edge ILP, 4 iterations.
__global__ __launch_bounds__(512) void cscatter_kernel(
    const int* __restrict__ src, const int* __restrict__ dst,
    const int* __restrict__ et, const float* __restrict__ m1,
    const float* __restrict__ m2, int* __restrict__ ccur,
    int4* __restrict__ tmp, int* __restrict__ mark) {
    __shared__ int lh[NCB];
    __shared__ int lbase[NCB];
    int tid = threadIdx.x;        // 0..511
    lh[tid] = 0;
    __syncthreads();
    int e0b = blockIdx.x * CBSZ;
#pragma unroll
    for (int j = 0; j < CBSZ / 2048; j++) {          // 4 iters
        int4 d4 = *(const int4*)(dst + e0b + j * 2048 + tid * 4);
        atomicAdd(&lh[d4.x >> 8], 1);
        atomicAdd(&lh[d4.y >> 8], 1);
        atomicAdd(&lh[d4.z >> 8], 1);
        atomicAdd(&lh[d4.w >> 8], 1);
    }
    __syncthreads();
    int c = lh[tid];
    lbase[tid] = c ? atomicAdd(&ccur[tid], c) : 0;   // returning, 512/block
    lh[tid] = 0;                 // reuse as local cursor (own-slot only)
    __syncthreads();
#pragma unroll
    for (int j = 0; j < CBSZ / 2048; j++) {
        int e0 = e0b + j * 2048 + tid * 4;
        int4  d4 = *(const int4*)(dst + e0);
        int4  s4 = *(const int4*)(src + e0);
        int4  t4 = *(const int4*)(et + e0);
        float4 a4 = *(const float4*)(m1 + e0);
        float4 b4 = *(const float4*)(m2 + e0);
#pragma unroll
        for (int k = 0; k < 4; k++) {
            int d = (&d4.x)[k];
            int s = (&s4.x)[k];
            int b = d >> 8;
            int r = atomicAdd(&lh[b], 1);            // LDS returning
            int4 v;
            v.x = s | ((&t4.x)[k] << 20);
            v.y = __float_as_int((&a4.x)[k]);
            v.z = __float_as_int((&b4.x)[k]);
            v.w = d;
            tmp[lbase[b] + r] = v;
            if (d < BSUB) mark[s] = 1;               // benign race: all write 1
        }
    }
}

// ---------------- pass C: fine scatter within coarse bucket + offs write -------
// 512 blocks (2/CU), one per bucket (256 nodes, ~4096 edges, 64 KB csr region).
__global__ __launch_bounds__(256) void fscatter_kernel(
    const int4* __restrict__ tmp, const int* __restrict__ cbase,
    const int* __restrict__ chist, int* __restrict__ offs,
    int4* __restrict__ csr) {
    __shared__ int lh[256];
    __shared__ int lpre[256];
    __shared__ int s[256];
    int b = blockIdx.x;
    int tid = threadIdx.x;
    int base = cbase[b], cnt = chist[b];
    lh[tid] = 0;
    __syncthreads();
    int i = 0;
    for (; i + 1024 <= cnt; i += 1024) {
        int4 v0 = tmp[base + i + tid * 4 + 0];
        int4 v1 = tmp[base + i + tid * 4 + 1];
        int4 v2 = tmp[base + i + tid * 4 + 2];
        int4 v3 = tmp[base + i + tid * 4 + 3];
        atomicAdd(&lh[v0.w & 255], 1);
        atomicAdd(&lh[v1.w & 255], 1);
        atomicAdd(&lh[v2.w & 255], 1);
        atomicAdd(&lh[v3.w & 255], 1);
    }
    for (int k = i + tid; k < cnt; k += 256)
        atomicAdd(&lh[tmp[base + k].w & 255], 1);
    __syncthreads();
    // exclusive scan of 256 bins
    int v = lh[tid];
    s[tid] = v;
    __syncthreads();
    int val = v;
    for (int off = 1; off < 256; off <<= 1) {
        int tq = (tid >= off) ? s[tid - off] : 0;
        __syncthreads();
        val += tq;
        s[tid] = val;
        __syncthreads();
    }
    int ex = val - v;
    lpre[tid] = ex;
    offs[b * 256 + tid] = base + ex;     // offs for this bucket's 256 nodes
    lh[tid] = 0;                          // reuse as cursors
    __syncthreads();
    i = 0;
    for (; i + 1024 <= cnt; i += 1024) {
        int4 v0 = tmp[base + i + tid * 4 + 0];
        int4 v1 = tmp[base + i + tid * 4 + 1];
        int4 v2 = tmp[base + i + tid * 4 + 2];
        int4 v3 = tmp[base + i + tid * 4 + 3];
        int k0 = v0.w & 255; int r0 = atomicAdd(&lh[k0], 1); csr[base + lpre[k0] + r0] = v0;
        int k1 = v1.w & 255; int r1 = atomicAdd(&lh[k1], 1); csr[base + lpre[k1] + r1] = v1;
        int k2 = v2.w & 255; int r2 = atomicAdd(&lh[k2], 1); csr[base + lpre[k2] + r2] = v2;
        int k3 = v3.w & 255; int r3 = atomicAdd(&lh[k3], 1); csr[base + lpre[k3] + r3] = v3;
    }
    for (int kk = i + tid; kk < cnt; kk += 256) {
        int4 vv = tmp[base + kk];
        int k = vv.w & 255;
        int r = atomicAdd(&lh[k], 1);
        csr[base + lpre[k] + r] = vv;                // .w carries dst (agg ignores)
    }
}

// block-level exclusive scan of 256 ints; block total -> bsum (mark compaction)
__global__ void scan1_kernel(const int* __restrict__ cnt, int* __restrict__ scanned,
                             int* __restrict__ bsum) {
    __shared__ int s[256];
    int tid = threadIdx.x;
    int i = blockIdx.x * 256 + tid;
    int v = cnt[i];
    s[tid] = v;
    __syncthreads();
    int val = v;
    for (int off = 1; off < 256; off <<= 1) {
        int tmp = (tid >= off) ? s[tid - off] : 0;
        __syncthreads();
        val += tmp;
        s[tid] = val;
        __syncthreads();
    }
    scanned[i] = val - v;                 // exclusive
    if (tid == 255) bsum[blockIdx.x] = val;
}

// exclusive scan of 512 block sums, in place
__global__ void scan2_kernel(int* __restrict__ bsum) {
    __shared__ int s[512];
    int tid = threadIdx.x;
    int v = bsum[tid];
    s[tid] = v;
    __syncthreads();
    int val = v;
    for (int off = 1; off < 512; off <<= 1) {
        int tmp = (tid >= off) ? s[tid - off] : 0;
        __syncthreads();
        val += tmp;
        s[tid] = val;
        __syncthreads();
    }
    bsum[tid] = val - v;
}

// compact marked nodes -> list[], write count to nld
__global__ void listfill_kernel(const int* __restrict__ mark, const int* __restrict__ mpref,
                                const int* __restrict__ mbsum, int* __restrict__ list,
                                int* __restrict__ nld) {
    int i = blockIdx.x * 256 + threadIdx.x;
    int pos = mpref[i] + mbsum[blockIdx.x];
    if (mark[i]) list[pos] = i;
    if (i == N_NODES - 1) *nld = pos + mark[i];
}

// ---------------- x -> bf16 convert ----------------
__global__ void cvt_kernel(const float4* __restrict__ x, ushort4* __restrict__ hb, int n4) {
    int i = blockIdx.x * 256 + threadIdx.x;
    if (i < n4) hb[i] = f4_to_bf4(x[i]);
}

// ---------------- weight packing into MFMA B-fragment layout ----------------
// Wc[192][64]: rows 0..63 = V_b0, 64..127 = V_b1, 128..191 = W_self.
// wfrag[conv][nt(4)][kidx(6)][lane(64)][j(8)]; n = nt*16+(lane&15),
// k = kidx*32+(lane>>4)*8+j.
__global__ void wpack_kernel(const float* __restrict__ lV, const float* __restrict__ lW,
                             const float* __restrict__ gV, const float* __restrict__ gW,
                             u16* __restrict__ wfrag) {
    int idx = blockIdx.x * 256 + threadIdx.x;   // 6*4*6*64 = 9216
    if (idx >= 6 * 4 * 6 * 64) return;
    int lane = idx & 63;
    int kidx = (idx >> 6) % 6;
    int nt   = (idx >> 6) / 6 % 4;
    int c    = idx / (64 * 6 * 4);      // conv 0..5
    int layer = c >> 1;
    bool isglobal = c & 1;
    const float* V = isglobal ? gV : lV;
    const float* W = isglobal ? gW : lW;
    int n = nt * 16 + (lane & 15);
    int kbase = kidx * 32 + (lane >> 4) * 8;
    u16 vals[8];
#pragma unroll
    for (int j = 0; j < 8; j++) {
        int r = kbase + j;      // 0..191
        float val;
        if (r < NBASES * DIM) {
            int b = r >> 6, d = r & 63;
            val = V[((layer * NBASES + b) * DIM + d) * DIM + n];
        } else {
            int d = r - NBASES * DIM;
            val = W[(layer * DIM + d) * DIM + n];
        }
        vals[j] = f2bf(val);
    }
    ushort4* o = (ushort4*)(wfrag + (size_t)idx * 8);
    o[0] = make_ushort4(vals[0], vals[1], vals[2], vals[3]);
    o[1] = make_ushort4(vals[4], vals[5], vals[6], vals[7]);
}

// ---------------- R22 fused conv: agg (16 nodes/block) + MFMA gemm + act -------
// Block = 4 waves. Agg phase: wave w aggregates nodes slot0+w*4+i (i=0..3)
// with the R18/R20 structure (LDS meta-stage, 16-slot straight-line groups),
// writing t-rows to LDS t_tile[16][34] (padded: 2-way bank alias only).
// Gemm phase: wave w computes cols w*16..w*16+15 for all 16 rows via
// 6x mfma_f32_16x16x32_bf16 (kidx 0-3 A from t_tile, 4-5 A from hb self-row),
// then bias+act+store to hout (ping-pong buffer) and subg.
__global__ __launch_bounds__(256) void aggmm_kernel(
    const ushort4* __restrict__ hb, const int* __restrict__ offs,
    const int4* __restrict__ csr, const float* __restrict__ Cc,
    int which, const u16* __restrict__ wfrag, const float* __restrict__ bias,
    u16* __restrict__ hout, float* __restrict__ subg, int subg_off, int act,
    int nNodes, const int* __restrict__ list, const int* __restrict__ nld) {
    __shared__ int4 lmeta[4][64];
    __shared__ alignas(16) ushort4 t_tile[16][34];   // 16 rows x 256B, +16B pad
    int lane = threadIdx.x & 63;
    int wid  = threadIdx.x >> 6;
    int q  = lane >> 4;     // quarter 0..3
    int ql = lane & 15;     // lane within quarter
    int nld_v = list ? *nld : 0;
    int slot0 = blockIdx.x << 4;
    if (list && slot0 >= nld_v) return;              // uniform whole-block exit
    float Ca0 = Cc[0], Cb0 = Cc[1], Ca1 = Cc[2], Cb1 = Cc[3], Ca2 = Cc[4], Cb2 = Cc[5];

    // ---- agg phase: 4 nodes per wave, sequential ----
    for (int i = 0; i < 4; i++) {
        int slot = slot0 + (wid << 2) + i;
        int n = -1;
        if (list) { if (slot < nld_v) n = list[slot]; }
        else if (slot < nNodes) n = slot;
        float4 a0 = make_float4(0.f, 0.f, 0.f, 0.f);
        float4 a1 = make_float4(0.f, 0.f, 0.f, 0.f);
        if (n >= 0) {
            int beg = offs[n], end = offs[n + 1];
            for (int base = beg; base < end; base += 64) {
                int cnt = min(64, end - base);
                int pp = 0; float c0 = 0.f, c1 = 0.f;
                if (lane < cnt) {
                    int4 meta = csr[base + lane];
                    int et = ((unsigned)meta.x) >> 20;
                    float m = __int_as_float(which ? meta.z : meta.y);
                    float ca = et == 0 ? Ca0 : (et == 1 ? Ca1 : Ca2);
                    float cb = et == 0 ? Cb0 : (et == 1 ? Cb1 : Cb2);
                    pp = (meta.x & 0xFFFFF) << 4;    // pre-scaled hb row base
                    c0 = m * ca;
                    c1 = m * cb;
                }
                lmeta[wid][lane] = make_int4(pp, __float_as_int(c0), __float_as_int(c1), 0);
                for (int j = 0; j < cnt; j += 16) {
#pragma unroll
                    for (int s = 0; s < 4; s++) {
                        int4 md = lmeta[wid][j + (s << 2) + q];   // quarter broadcast
                        ushort4 rv = hb[md.x + ql];
                        float4 v = bf4_to_f4(rv);
                        float e0 = __int_as_float(md.y);
                        float e1 = __int_as_float(md.z);
                        a0.x = fmaf(e0, v.x, a0.x); a0.y = fmaf(e0, v.y, a0.y);
                        a0.z = fmaf(e0, v.z, a0.z); a0.w = fmaf(e0, v.w, a0.w);
                        a1.x = fmaf(e1, v.x, a1.x); a1.y = fmaf(e1, v.y, a1.y);
                        a1.z = fmaf(e1, v.z, a1.z); a1.w = fmaf(e1, v.w, a1.w);
                    }
                }
            }
#pragma unroll
            for (int off = 16; off < 64; off <<= 1) {
                a0.x += __shfl_xor(a0.x, off, 64); a0.y += __shfl_xor(a0.y, off, 64);
                a0.z += __shfl_xor(a0.z, off, 64); a0.w += __shfl_xor(a0.w, off, 64);
                a1.x += __shfl_xor(a1.x, off, 64); a1.y += __shfl_xor(a1.y, off, 64);
                a1.z += __shfl_xor(a1.z, off, 64); a1.w += __shfl_xor(a1.w, off, 64);
            }
            if (q < 2)
                t_tile[(wid << 2) + i][(q << 4) + ql] = f4_to_bf4(q == 0 ? a0 : a1);
        }
    }
    __syncthreads();

    // ---- gemm phase: wave w -> 16 rows x cols [w*16, w*16+16) ----
    int l16 = ql;          // lane & 15
    int quad = q;          // lane >> 4
    int myslot = slot0 + l16;
    int rowA = list ? list[min(myslot, nld_v - 1)] : min(myslot, nNodes - 1);
    const u16* hrow = (const u16*)hb + (size_t)rowA * 64;
    const u16* trow = (const u16*)&t_tile[l16][0];
    f32x4 acc = {0.f, 0.f, 0.f, 0.f};
#pragma unroll
    for (int kidx = 0; kidx < 6; kidx++) {
        bf16x8 a = (kidx < 4)
            ? *(const bf16x8*)(trow + kidx * 32 + quad * 8)
            : *(const bf16x8*)(hrow + (kidx - 4) * 32 + quad * 8);
        bf16x8 b = *(const bf16x8*)(wfrag + ((size_t)(wid * 6 + kidx) * 64 + lane) * 8);
        acc = __builtin_amdgcn_mfma_f32_16x16x32_bf16(a, b, acc, 0, 0, 0);
    }
    int col = wid * 16 + l16;
    float bcol = bias[col];
#pragma unroll
    for (int r = 0; r < 4; r++) {
        int cslot = slot0 + quad * 4 + r;
        if (list && cslot >= nld_v) continue;
        int row = list ? __shfl(rowA, quad * 4 + r, 64) : cslot;
        float xv = acc[r] + bcol;
        float v = act ? (xv > 0.f ? xv : 0.01f * xv)
                      : (xv > 0.f ? xv : expm1f(xv));
        hout[(size_t)row * 64 + col] = f2bf(v);
        if (subg && row < BSUB)
            subg[(size_t)row * 192 + subg_off + col] = v;
    }
}

// ---------------- MLP head: [4096,192] -> relu 128 -> sigmoid 1 ----------------
__global__ __launch_bounds__(256) void head_kernel(
    const float* __restrict__ subg, const float* __restrict__ w1,
    const float* __restrict__ b1, const float* __restrict__ w2,
    const float* __restrict__ b2, float* __restrict__ out) {
    __shared__ float srow[4][192];
    int lane = threadIdx.x & 63, wid = threadIdx.x >> 6;
    int row = blockIdx.x * 4 + wid;
    const float* sr = subg + (size_t)row * 192;
    srow[wid][lane] = sr[lane];
    srow[wid][64 + lane] = sr[64 + lane];
    srow[wid][128 + lane] = sr[128 + lane];
    __syncthreads();
    float acc1 = b1[lane], acc2 = b1[64 + lane];
    const float* w1a = w1 + lane * 192;
    const float* w1b = w1 + (64 + lane) * 192;
    for (int k = 0; k < 192; k++) {
        float s = srow[wid][k];
        acc1 = fmaf(s, w1a[k], acc1);
        acc2 = fmaf(s, w1b[k], acc2);
    }
    acc1 = fmaxf(acc1, 0.f);
    acc2 = fmaxf(acc2, 0.f);
    float part = acc1 * w2[lane] + acc2 * w2[64 + lane];
    for (int off = 32; off; off >>= 1) part += __shfl_down(part, off, 64);
    if (lane == 0) out[row] = 1.f / (1.f + expf(-(part + b2[0])));
}

extern "C" void kernel_launch(void* const* d_in, const int* in_sizes, int n_in,
                              void* d_out, int out_size, void* d_ws, size_t ws_size,
                              hipStream_t stream) {
    const float* x     = (const float*)d_in[0];
    const int*   src   = (const int*)d_in[1];
    const int*   dst   = (const int*)d_in[2];
    const int*   etype = (const int*)d_in[3];
    const float* mask  = (const float*)d_in[4];
    const float* mask2 = (const float*)d_in[5];
    const float* lV = (const float*)d_in[6];
    const float* lC = (const float*)d_in[7];
    const float* lW = (const float*)d_in[8];
    const float* lB = (const float*)d_in[9];
    const float* gV = (const float*)d_in[10];
    const float* gC = (const float*)d_in[11];
    const float* gW = (const float*)d_in[12];
    const float* gB = (const float*)d_in[13];
    const float* w1 = (const float*)d_in[14];
    const float* b1 = (const float*)d_in[15];
    const float* w2 = (const float*)d_in[16];
    const float* b2 = (const float*)d_in[17];
    float* out = (float*)d_out;

    // workspace carve-up
    char* ws = (char*)d_ws;
    size_t off = 0;
    auto alloc = [&](size_t bytes) {
        void* p = ws + off;
        off += (bytes + 255) & ~(size_t)255;
        return p;
    };
    ushort4* h0   = (ushort4*)alloc((size_t)N_NODES * 64 * 2);     // bf16 [N,64]
    ushort4* h1   = (ushort4*)alloc((size_t)N_NODES * 64 * 2);     // ping-pong
    int4*  csr    = (int4*)alloc((size_t)N_EDGES * 16);
    int*   offs   = (int*)alloc((size_t)(N_NODES + 1) * 4);
    int*   chist  = (int*)alloc(NCB * 4);
    int*   cbase  = (int*)alloc(NCB * 4);
    int*   ccur   = (int*)alloc(NCB * 4);
    int*   bsum   = (int*)alloc(512 * 4);
    int*   mark   = (int*)alloc((size_t)N_NODES * 4);
    int*   mpref  = (int*)alloc((size_t)N_NODES * 4);
    int*   mbsum  = (int*)alloc(512 * 4);
    int*   list   = (int*)alloc((size_t)N_NODES * 4);
    int*   nld    = (int*)alloc(256);
    u16*   wfrag  = (u16*)alloc((size_t)6 * 4 * 6 * 64 * 8 * 2);
    float* subg   = (float*)alloc((size_t)BSUB * 192 * 4);
    // tmp (coarse-sorted payload, 32 MB) aliases h0+h1 (contiguous, dead until
    // cvt/conv which run after fscatter).
    int4*  tmp    = (int4*)h0;

    // ---- graph preprocessing (R17/R21 sort pipeline) ----
    initmark_kernel<<<N_NODES / 256, 256, 0, stream>>>(mark, chist);
    chist_kernel<<<N_EDGES / CBSZ, 256, 0, stream>>>(dst, chist);
    cscan_kernel<<<1, NCB, 0, stream>>>(chist, cbase, ccur, offs);
    cscatter_kernel<<<N_EDGES / CBSZ, 512, 0, stream>>>(src, dst, etype, mask, mask2,
                                                        ccur, tmp, mark);
    fscatter_kernel<<<NCB, 256, 0, stream>>>(tmp, cbase, chist, offs, csr);
    // frontier compaction for layer-2 local conv
    scan1_kernel<<<N_NODES / 256, 256, 0, stream>>>(mark, mpref, mbsum);
    scan2_kernel<<<1, 512, 0, stream>>>(mbsum);
    listfill_kernel<<<N_NODES / 256, 256, 0, stream>>>(mark, mpref, mbsum, list, nld);
    wpack_kernel<<<(6 * 4 * 6 * 64 + 255) / 256, 256, 0, stream>>>(lV, lW, gV, gW, wfrag);
    // cvt AFTER fscatter: h0 aliases tmp
    cvt_kernel<<<(N_NODES * 64 / 4) / 256, 256, 0, stream>>>((const float4*)x, h0,
                                                             N_NODES * 64 / 4);

    const int convfrag = 4 * 6 * 64 * 8;   // u16 elements per conv
    ushort4* hb[2] = {h0, h1};
    int cur = 0;
    for (int layer = 0; layer < 3; layer++) {
        // local conv (mask, elu); layer 2: frontier-pruned (early-exit blocks)
        const int* ll = (layer == 2) ? list : nullptr;
        aggmm_kernel<<<N_NODES / 16, 256, 0, stream>>>(
            hb[cur], offs, csr, lC + layer * NREL * NBASES, 0,
            wfrag + (size_t)(layer * 2 + 0) * convfrag, lB + layer * 64,
            (u16*)hb[cur ^ 1], nullptr, 0, 0, N_NODES, ll, nld);
        cur ^= 1;
        // global conv (mask2, leaky_relu); layer 2: only BSUB rows
        int nG = (layer == 2) ? BSUB : N_NODES;
        aggmm_kernel<<<nG / 16, 256, 0, stream>>>(
            hb[cur], offs, csr, gC + layer * NREL * NBASES, 1,
            wfrag + (size_t)(layer * 2 + 1) * convfrag, gB + layer * 64,
            (u16*)hb[cur ^ 1], subg, layer * 64, 1, nG, nullptr, nld);
        cur ^= 1;
    }
    head_kernel<<<BSUB / 4, 256, 0, stream>>>(subg, w1, b1, w2, b2, out);
}